// Round 11
// baseline (934.426 us; speedup 1.0000x reference)
//
#include <hip/hip_runtime.h>

#define N_ATOMS 100000
#define N_EDGES 3200000
#define N_RBF 8
#define HIDDEN 16

#define NB 4096
#define TSCALE 64.0f   // bins per unit r2; table covers r2 in [0, 64)

// d_out layout (floats):
#define OFF_TE   0
#define OFF_NE   1
#define OFF_F    (1 + N_ATOMS)
#define OFF_VIR  (1 + N_ATOMS + 3*N_ATOMS)
#define OFF_AV   (OFF_VIR + 9)

#define BSH   5
#define BAT   32                        // atoms per bucket
#define NBUCK 3125                      // 100000/32 exactly
#define BPAD  3136                      // padded bucket count (64-aligned)

// ---- new-path ws layout (words) ----
#define NTAB_S   0
#define NTAB_G   (NB*HIDDEN)
#define NBKC_R8  (2*NB*HIDDEN)                // 131072; 8 per-XCD recv-bucket counters
#define NBKC_S8  (NBKC_R8 + 8*BPAD)
#define NBKO_R   (NBKC_S8 + 8*BPAD)           // bucket base offsets (NBUCK+1)
#define NBKO_S   (NBKO_R + BPAD)
#define NTEP     (NBKO_S + BPAD)
#define NVPART   (NTEP + BPAD)
#define NAV6R    (NVPART + 6*BPAD)            // recv-side per-atom virial (6*N)
#define NSTGR    (NAV6R + 6*N_ATOMS)          // recv-bucket staging float4[E]
#define NSTGS    (NSTGR + 4*N_EDGES)          // send-bucket staging float4[E]
#define NSLS     (NSTGS + 4*N_EDGES)          // send_lo u8[E]
#define NEND     (NSLS + N_EDGES/4)           // 27,209,472 words = 108.8 MB

// ---- fallback (round-3) ws layout ----
#define WPAD (N_ATOMS + 4)
#define WOFF_OFFS_R 0
#define WOFF_OFFS_S WPAD
#define WOFF_RANK_R (2*WPAD)
#define WOFF_RANK_S (WOFF_RANK_R + N_EDGES)
#define WOFF_EID_R  (WOFF_RANK_S + N_EDGES)
#define WOFF_EID_S  (WOFF_EID_R + N_EDGES)
#define WOFF_DR2    (WOFF_EID_S + N_EDGES)
#define WOFF_AV6    (WOFF_DR2 + N_EDGES)
#define WOFF_END    (WOFF_AV6 + 6*N_ATOMS)

__device__ inline unsigned int get_xcd() {
    unsigned int xcd;
    asm volatile("s_getreg_b32 %0, hwreg(HW_REG_XCC_ID)" : "=s"(xcd));
    return xcd & 7;
}

// ---------------- table build ----------------
__global__ void build_tables(const float* __restrict__ W1, const float* __restrict__ b1,
                             const float* __restrict__ alphas,
                             float* __restrict__ s_tab, float* __restrict__ g_tab) {
    int idx = blockIdx.x * blockDim.x + threadIdx.x;   // NB*HIDDEN = 65536
    int b = idx >> 4, j = idx & 15;
    float r2 = (float)b / TSCALE;
    float pre = b1[j], pw = 0.f;
    #pragma unroll
    for (int f = 0; f < N_RBF; ++f) {
        float al = alphas[f];
        float ph = __expf(-r2 * al);
        float w  = W1[f*HIDDEN + j];
        pre += ph * w;
        pw  += al * ph * w;
    }
    float sig = 1.f / (1.f + __expf(-pre));
    s_tab[idx] = pre * sig;
    g_tab[idx] = sig * (1.f + pre * (1.f - sig)) * pw;
}

// ---------------- bucket counting: per-XCD, L2-local int atomics ----------------

__global__ void bucket_count(const int* __restrict__ ei,
                             int* __restrict__ bkc_r8, int* __restrict__ bkc_s8) {
    unsigned int xcd = get_xcd();
    int e = blockIdx.x * blockDim.x + threadIdx.x;
    if (e >= N_EDGES) return;
    int send = ei[e], recv = ei[N_EDGES + e];
    __hip_atomic_fetch_add(&bkc_r8[xcd*BPAD + (recv >> BSH)], 1,
                           __ATOMIC_RELAXED, __HIP_MEMORY_SCOPE_WORKGROUP);
    __hip_atomic_fetch_add(&bkc_s8[xcd*BPAD + (send >> BSH)], 1,
                           __ATOMIC_RELAXED, __HIP_MEMORY_SCOPE_WORKGROUP);
}

// per-bucket: xcd-exclusive bases in place; then exclusive scan of bucket totals.
__global__ void bucket_prefix(int* __restrict__ bkc_r8, int* __restrict__ bkc_s8,
                              int* __restrict__ bko_r, int* __restrict__ bko_s) {
    int* cnt8 = blockIdx.x ? bkc_s8 : bkc_r8;
    int* offs = blockIdx.x ? bko_s : bko_r;
    int tid = threadIdx.x;
    for (int b = tid; b < NBUCK; b += 1024) {
        int t = 0;
        #pragma unroll
        for (int x = 0; x < 8; ++x) {
            int c = cnt8[x*BPAD + b];
            cnt8[x*BPAD + b] = t;
            t += c;
        }
        offs[b] = t;
    }
    if (tid == 0) offs[NBUCK] = 0;
    __syncthreads();
    const int n = NBUCK + 1;
    __shared__ int wsum[16];
    __shared__ int carry;
    if (tid == 0) carry = 0;
    __syncthreads();
    int lane = tid & 63, w = tid >> 6;
    for (int base = 0; base < n; base += 1024) {
        int i = base + tid;
        int v = (i < n) ? offs[i] : 0;
        int s = v;
        #pragma unroll
        for (int o = 1; o < 64; o <<= 1) {
            int t2 = __shfl_up(s, o);
            if (lane >= o) s += t2;
        }
        if (lane == 63) wsum[w] = s;
        __syncthreads();
        if (tid < 16) {
            int sc = wsum[tid];
            #pragma unroll
            for (int o = 1; o < 16; o <<= 1) {
                int t2 = __shfl_up(sc, o);
                if (tid >= o) sc += t2;
            }
            wsum[tid] = sc;
        }
        __syncthreads();
        int wpre = (w > 0) ? wsum[w-1] : 0;
        int cb = carry;
        if (i < n) offs[i] = s - v + wpre + cb;
        __syncthreads();
        if (tid == 0) carry = cb + wsum[15];
        __syncthreads();
    }
}

// ---------------- scatter into recv buckets (plain stores: L2 tail-merging) ----
// stgR[pr] = (vx,vy,vz, bitcast(recv_lo5 | send<<5))
__global__ void scatterB(const int* __restrict__ ei,
                         const int* __restrict__ bko_r, int* __restrict__ bkc_r8,
                         const float* __restrict__ vectors,
                         float4* __restrict__ stgR) {
    unsigned int xcd = get_xcd();
    int e = blockIdx.x * blockDim.x + threadIdx.x;
    if (e >= N_EDGES) return;
    int send = ei[e], recv = ei[N_EDGES + e];
    int rb = recv >> BSH;
    int p = __hip_atomic_fetch_add(&bkc_r8[xcd*BPAD + rb], 1,
                                   __ATOMIC_RELAXED, __HIP_MEMORY_SCOPE_WORKGROUP);
    int pr = bko_r[rb] + p;
    float vx = vectors[3*e], vy = vectors[3*e+1], vz = vectors[3*e+2];
    int packed = (recv & 31) | (send << BSH);
    stgR[pr] = make_float4(vx, vy, vz, __int_as_float(packed));
}

// ---------------- fused per recv-bucket: fwd(LDS h) + node MLP + bwd ----------
// pass 2 appends (v,dr2)+send_lo to send buckets (L2 tail-merged).

__global__ __launch_bounds__(512) void fusedB(
        const float4* __restrict__ stgR,
        const float* __restrict__ positions, const float* __restrict__ lg,
        const float* __restrict__ W2, const float* __restrict__ w3,
        const float* __restrict__ field,
        const int* __restrict__ bko_r, const int* __restrict__ bko_s,
        int* __restrict__ bkc_s8,
        const float* __restrict__ s_tab, const float* __restrict__ g_tab,
        float4* __restrict__ stgS, unsigned char* __restrict__ slS,
        float* __restrict__ av6r, float* __restrict__ tepart,
        float* __restrict__ out) {
    unsigned int xcd = get_xcd();
    int b = blockIdx.x;
    int tid = threadIdx.x;
    int base = bko_r[b], nE = bko_r[b+1] - base;

    __shared__ float hl[BAT*17];     // h accum, padded rows
    __shared__ float gl[BAT*16];     // per-atom g vectors
    __shared__ float virl[BAT*6];    // recv-side virial
    __shared__ float red[8];

    for (int q = tid; q < BAT*17; q += 512) hl[q] = 0.f;
    for (int q = tid; q < BAT*6;  q += 512) virl[q] = 0.f;
    __syncthreads();

    // ---- pass 1: forward, h accumulated in LDS ----
    for (int k = tid; k < nE; k += 512) {
        float4 p = stgR[base + k];
        int rl = __float_as_int(p.w) & 31;
        float r2 = p.x*p.x + p.y*p.y + p.z*p.z;
        float x = fminf(r2 * TSCALE, (float)(NB - 2) + 0.999f);
        int i = (int)x;
        float f = x - (float)i;
        const float4* r0 = (const float4*)(s_tab + i * HIDDEN);
        const float4* r1 = (const float4*)(s_tab + (i + 1) * HIDDEN);
        float* hrow = hl + rl*17;
        #pragma unroll
        for (int q = 0; q < 4; ++q) {
            float4 A = r0[q], B = r1[q];
            atomicAdd(hrow + 4*q + 0, A.x + f*(B.x-A.x));
            atomicAdd(hrow + 4*q + 1, A.y + f*(B.y-A.y));
            atomicAdd(hrow + 4*q + 2, A.z + f*(B.z-A.z));
            atomicAdd(hrow + 4*q + 3, A.w + f*(B.w-A.w));
        }
    }
    __syncthreads();

    // ---- node MLP: thread = (atom aL = tid>>4, channel ch = tid&15) ----
    int aL = tid >> 4, ch = tid & 15;
    int lane = tid & 63, gb = lane & 48;
    int atom = b*BAT + aL;
    float aj = 0.f;
    const float* hrow = hl + aL*17;
    #pragma unroll
    for (int i = 0; i < HIDDEN; ++i) aj += hrow[i] * W2[i*HIDDEN + ch];
    float sigj = 1.f / (1.f + __expf(-aj));
    float l = lg[atom];
    float w3j = w3[ch];
    float sd = aj * sigj * w3j;
    #pragma unroll
    for (int o = 1; o < 16; o <<= 1) sd += __shfl_xor(sd, o);
    float dAj = l * w3j * sigj * (1.f + aj * (1.f - sigj));
    float gown = 0.f;
    #pragma unroll
    for (int q = 0; q < HIDDEN; ++q) {
        float dq = __shfl(dAj, gb | q);
        gown += dq * W2[ch*HIDDEN + q];
    }
    gl[aL*16 + ch] = gown;
    float contrib = 0.f;
    if (ch == 0) {
        float ne = sd + positions[3*atom]*field[0] + positions[3*atom+1]*field[1]
                      + positions[3*atom+2]*field[2];
        out[OFF_NE + atom] = ne;
        out[OFF_F + 3*atom + 0] = -l * field[0];
        out[OFF_F + 3*atom + 1] = -l * field[1];
        out[OFF_F + 3*atom + 2] = -l * field[2];
        contrib = ne * l;
    }
    contrib += __shfl_xor(contrib, 16);
    contrib += __shfl_xor(contrib, 32);
    if (lane == 0) red[tid >> 6] = contrib;
    __syncthreads();   // gl + red ready

    // ---- pass 2: backward; recv virial in LDS; send append to buckets ----
    for (int k = tid; k < nE; k += 512) {
        float4 p = stgR[base + k];
        int pk = __float_as_int(p.w);
        int rl = pk & 31;
        int send = ((unsigned)pk) >> BSH;
        float r2 = p.x*p.x + p.y*p.y + p.z*p.z;
        float x = fminf(r2 * TSCALE, (float)(NB - 2) + 0.999f);
        int i = (int)x;
        float f = x - (float)i;
        const float4* r0 = (const float4*)(g_tab + i * HIDDEN);
        const float4* r1 = (const float4*)(g_tab + (i + 1) * HIDDEN);
        const float4* gr = (const float4*)(gl + rl*16);
        float dr2 = 0.f;
        #pragma unroll
        for (int q = 0; q < 4; ++q) {
            float4 A = r0[q], B = r1[q];
            float4 G = gr[q];
            dr2 -= G.x * (A.x + f*(B.x-A.x));
            dr2 -= G.y * (A.y + f*(B.y-A.y));
            dr2 -= G.z * (A.z + f*(B.z-A.z));
            dr2 -= G.w * (A.w + f*(B.w-A.w));
        }
        float* vr = virl + rl*6;
        atomicAdd(vr+0, dr2*p.x*p.x);
        atomicAdd(vr+1, dr2*p.x*p.y);
        atomicAdd(vr+2, dr2*p.x*p.z);
        atomicAdd(vr+3, dr2*p.y*p.y);
        atomicAdd(vr+4, dr2*p.y*p.z);
        atomicAdd(vr+5, dr2*p.z*p.z);
        int sb = send >> BSH;
        int q2 = __hip_atomic_fetch_add(&bkc_s8[xcd*BPAD + sb], 1,
                                        __ATOMIC_RELAXED, __HIP_MEMORY_SCOPE_WORKGROUP);
        int ps = bko_s[sb] + q2;
        stgS[ps] = make_float4(p.x, p.y, p.z, dr2);
        slS[ps] = (unsigned char)(send & 31);
    }
    __syncthreads();
    for (int q = tid; q < BAT*6; q += 512)
        av6r[(size_t)b*BAT*6 + q] = virl[q];
    if (tid == 0) {
        float s = 0.f;
        #pragma unroll
        for (int q = 0; q < 8; ++q) s += red[q];
        tepart[b] = s;
    }
}

// ---------------- send-bucket reduce + finalize atom_virial ----------------

__global__ __launch_bounds__(512) void bwd_sendB(
        const float4* __restrict__ stgS, const unsigned char* __restrict__ slS,
        const int* __restrict__ bko_s, const float* __restrict__ av6r,
        float* __restrict__ vpart, float* __restrict__ out) {
    int b = blockIdx.x;
    int tid = threadIdx.x;
    int base = bko_s[b], nE = bko_s[b+1] - base;
    __shared__ float virl[BAT*6];
    for (int q = tid; q < BAT*6; q += 512) virl[q] = 0.f;
    __syncthreads();
    for (int k = tid; k < nE; k += 512) {
        float4 p = stgS[base + k];
        int sl = slS[base + k];
        float dr2 = p.w;
        float* vr = virl + sl*6;
        atomicAdd(vr+0, dr2*p.x*p.x);
        atomicAdd(vr+1, dr2*p.x*p.y);
        atomicAdd(vr+2, dr2*p.x*p.z);
        atomicAdd(vr+3, dr2*p.y*p.y);
        atomicAdd(vr+4, dr2*p.y*p.z);
        atomicAdd(vr+5, dr2*p.z*p.z);
    }
    __syncthreads();
    if (tid < BAT) {
        int atom = b*BAT + tid;
        const float* ar = av6r + (size_t)atom*6;
        float s0 = virl[tid*6+0] + ar[0];
        float s1 = virl[tid*6+1] + ar[1];
        float s2 = virl[tid*6+2] + ar[2];
        float s3 = virl[tid*6+3] + ar[3];
        float s4 = virl[tid*6+4] + ar[4];
        float s5 = virl[tid*6+5] + ar[5];
        float* o9 = out + OFF_AV + (size_t)atom*9;
        o9[0] = s0; o9[1] = s1; o9[2] = s2;
        o9[3] = s1; o9[4] = s3; o9[5] = s4;
        o9[6] = s2; o9[7] = s4; o9[8] = s5;
        virl[tid*6+0] = s0; virl[tid*6+1] = s1; virl[tid*6+2] = s2;
        virl[tid*6+3] = s3; virl[tid*6+4] = s4; virl[tid*6+5] = s5;
    }
    __syncthreads();
    if (tid < 6) {
        float s = 0.f;
        #pragma unroll
        for (int a2 = 0; a2 < BAT; ++a2) s += virl[a2*6 + tid];
        vpart[b*6 + tid] = s;
    }
}

__global__ void finalize_kernel(const float* __restrict__ tepart,
                                const float* __restrict__ vpart,
                                float* __restrict__ out) {
    int t = threadIdx.x;
    float acc[7];
    #pragma unroll
    for (int c = 0; c < 7; ++c) acc[c] = 0.f;
    for (int i = t; i < NBUCK; i += 1024) {
        acc[0] += tepart[i];
        const float* p = vpart + (size_t)i * 6;
        acc[1] += p[0]; acc[2] += p[1]; acc[3] += p[2];
        acc[4] += p[3]; acc[5] += p[4]; acc[6] += p[5];
    }
    #pragma unroll
    for (int c = 0; c < 7; ++c) {
        #pragma unroll
        for (int o = 1; o < 64; o <<= 1) acc[c] += __shfl_xor(acc[c], o);
    }
    __shared__ float sh[16][8];
    int lane = t & 63, w = t >> 6;
    if (lane == 0) {
        #pragma unroll
        for (int c = 0; c < 7; ++c) sh[w][c] = acc[c];
    }
    __syncthreads();
    if (t == 0) {
        float s[7];
        #pragma unroll
        for (int c = 0; c < 7; ++c) {
            float v = 0.f;
            #pragma unroll
            for (int q = 0; q < 16; ++q) v += sh[q][c];
            s[c] = v;
        }
        out[OFF_TE] = s[0];
        out[OFF_VIR + 0] = s[1]; out[OFF_VIR + 1] = s[2]; out[OFF_VIR + 2] = s[3];
        out[OFF_VIR + 3] = s[2]; out[OFF_VIR + 4] = s[4]; out[OFF_VIR + 5] = s[5];
        out[OFF_VIR + 6] = s[3]; out[OFF_VIR + 7] = s[5]; out[OFF_VIR + 8] = s[6];
    }
}

// ================= fallback (round-3 verified path) =================

__global__ void count_kernel(const int* __restrict__ ei,
                             int* __restrict__ cnt_r, int* __restrict__ cnt_s,
                             int* __restrict__ rank_r, int* __restrict__ rank_s) {
    int e = blockIdx.x * blockDim.x + threadIdx.x;
    if (e >= N_EDGES) return;
    int send = ei[e], recv = ei[N_EDGES + e];
    rank_r[e] = atomicAdd(&cnt_r[recv], 1);
    rank_s[e] = atomicAdd(&cnt_s[send], 1);
}

__global__ void scan_kernel(int* __restrict__ offs_r, int* __restrict__ offs_s) {
    int* a = (blockIdx.x == 0) ? offs_r : offs_s;
    const int n = N_ATOMS + 1;
    __shared__ int wsum[4];
    __shared__ int carry_s;
    if (threadIdx.x == 0) carry_s = 0;
    __syncthreads();
    int lane = threadIdx.x & 63, w = threadIdx.x >> 6;
    for (int base = 0; base < n; base += 256) {
        int i = base + threadIdx.x;
        int v = (i < n) ? a[i] : 0;
        int s = v;
        #pragma unroll
        for (int o = 1; o < 64; o <<= 1) {
            int t = __shfl_up(s, o);
            if (lane >= o) s += t;
        }
        if (lane == 63) wsum[w] = s;
        __syncthreads();
        int wpre = 0;
        for (int k = 0; k < w; ++k) wpre += wsum[k];
        int incl = s + wpre;
        int total = wsum[0] + wsum[1] + wsum[2] + wsum[3];
        int excl = incl - v + carry_s;
        if (i < n) a[i] = excl;
        __syncthreads();
        if (threadIdx.x == 0) carry_s += total;
        __syncthreads();
    }
}

__global__ void scatter_kernel(const int* __restrict__ ei,
                               const int* __restrict__ offs_r, const int* __restrict__ offs_s,
                               const int* __restrict__ rank_r, const int* __restrict__ rank_s,
                               int* __restrict__ eid_r, int* __restrict__ eid_s) {
    int e = blockIdx.x * blockDim.x + threadIdx.x;
    if (e >= N_EDGES) return;
    int send = ei[e], recv = ei[N_EDGES + e];
    eid_r[offs_r[recv] + rank_r[e]] = e;
    eid_s[offs_s[send] + rank_s[e]] = e;
}

__global__ void fused_kernel(const float* __restrict__ vectors,
                             const float* __restrict__ positions,
                             const float* __restrict__ lg,
                             const float* __restrict__ W1, const float* __restrict__ b1,
                             const float* __restrict__ W2, const float* __restrict__ w3,
                             const float* __restrict__ field, const float* __restrict__ alphas,
                             const int* __restrict__ offs_r, const int* __restrict__ eid_r,
                             float* __restrict__ dr2buf, float* __restrict__ av6,
                             float* __restrict__ out) {
    int a = (blockIdx.x * blockDim.x + threadIdx.x) >> 6;
    int lane = threadIdx.x & 63;
    int start = offs_r[a], end = offs_r[a + 1];
    float al[N_RBF];
    #pragma unroll
    for (int f = 0; f < N_RBF; ++f) al[f] = alphas[f];
    float m[HIDDEN];
    #pragma unroll
    for (int j = 0; j < HIDDEN; ++j) m[j] = 0.f;
    float t[HIDDEN], paw[HIDDEN];
    float vx0 = 0.f, vy0 = 0.f, vz0 = 0.f;
    int e0 = -1;
    int k0 = start + lane;
    for (int k = k0; k < end; k += 64) {
        int e = eid_r[k];
        float vx = vectors[3*e], vy = vectors[3*e+1], vz = vectors[3*e+2];
        float r2 = vx*vx + vy*vy + vz*vz;
        float phi[N_RBF], apf[N_RBF];
        #pragma unroll
        for (int f = 0; f < N_RBF; ++f) { phi[f] = __expf(-r2 * al[f]); apf[f] = al[f] * phi[f]; }
        bool first = (k == k0);
        if (first) { e0 = e; vx0 = vx; vy0 = vy; vz0 = vz; }
        #pragma unroll
        for (int j = 0; j < HIDDEN; ++j) {
            float pre = b1[j];
            float pw = 0.f;
            #pragma unroll
            for (int f = 0; f < N_RBF; ++f) {
                float w = W1[f*HIDDEN + j];
                pre += phi[f] * w;
                pw  += apf[f] * w;
            }
            float sig = 1.f / (1.f + __expf(-pre));
            m[j] += pre * sig;
            if (first) { t[j] = sig * (1.f + pre * (1.f - sig)); paw[j] = pw; }
        }
    }
    #pragma unroll
    for (int o = 1; o < 64; o <<= 1) {
        #pragma unroll
        for (int j = 0; j < HIDDEN; ++j) m[j] += __shfl_xor(m[j], o);
    }
    int jj = lane & 15;
    int gbase = lane & 48;
    float aj = 0.f;
    #pragma unroll
    for (int i = 0; i < HIDDEN; ++i) aj += m[i] * W2[i*HIDDEN + jj];
    float sigj = 1.f / (1.f + __expf(-aj));
    float l = lg[a];
    float sd = aj * sigj * w3[jj];
    #pragma unroll
    for (int o = 1; o < 16; o <<= 1) sd += __shfl_xor(sd, o);
    float dAj = l * w3[jj] * sigj * (1.f + aj * (1.f - sigj));
    float dAv[HIDDEN];
    #pragma unroll
    for (int q = 0; q < HIDDEN; ++q) dAv[q] = __shfl(dAj, gbase | q);
    float gown = 0.f;
    #pragma unroll
    for (int j2 = 0; j2 < HIDDEN; ++j2) gown += dAv[j2] * W2[jj*HIDDEN + j2];
    float g[HIDDEN];
    #pragma unroll
    for (int q = 0; q < HIDDEN; ++q) g[q] = __shfl(gown, gbase | q);
    float contrib = 0.f;
    if (lane == 0) {
        float ne = sd + positions[3*a]*field[0] + positions[3*a+1]*field[1]
                      + positions[3*a+2]*field[2];
        out[OFF_NE + a] = ne;
        out[OFF_F + 3*a + 0] = -l * field[0];
        out[OFF_F + 3*a + 1] = -l * field[1];
        out[OFF_F + 3*a + 2] = -l * field[2];
        contrib = ne * l;
    }
    float axx=0.f, axy=0.f, axz=0.f, ayy=0.f, ayz=0.f, azz=0.f;
    if (k0 < end) {
        float dr2 = 0.f;
        #pragma unroll
        for (int j = 0; j < HIDDEN; ++j) dr2 -= (g[j] * t[j]) * paw[j];
        dr2buf[e0] = dr2;
        axx = dr2*vx0*vx0; axy = dr2*vx0*vy0; axz = dr2*vx0*vz0;
        ayy = dr2*vy0*vy0; ayz = dr2*vy0*vz0; azz = dr2*vz0*vz0;
    }
    for (int k = k0 + 64; k < end; k += 64) {
        int e = eid_r[k];
        float vx = vectors[3*e], vy = vectors[3*e+1], vz = vectors[3*e+2];
        float r2 = vx*vx + vy*vy + vz*vz;
        float phi[N_RBF], apf[N_RBF];
        #pragma unroll
        for (int f = 0; f < N_RBF; ++f) { phi[f] = __expf(-r2 * al[f]); apf[f] = al[f] * phi[f]; }
        float dr2 = 0.f;
        #pragma unroll
        for (int j = 0; j < HIDDEN; ++j) {
            float pre = b1[j];
            float pw = 0.f;
            #pragma unroll
            for (int f = 0; f < N_RBF; ++f) {
                float w = W1[f*HIDDEN + j];
                pre += phi[f] * w;
                pw  += apf[f] * w;
            }
            float sig = 1.f / (1.f + __expf(-pre));
            float tt = sig * (1.f + pre * (1.f - sig));
            dr2 -= (g[j] * tt) * pw;
        }
        dr2buf[e] = dr2;
        axx += dr2*vx*vx; axy += dr2*vx*vy; axz += dr2*vx*vz;
        ayy += dr2*vy*vy; ayz += dr2*vy*vz; azz += dr2*vz*vz;
    }
    #pragma unroll
    for (int o = 1; o < 64; o <<= 1) {
        axx += __shfl_xor(axx, o); axy += __shfl_xor(axy, o); axz += __shfl_xor(axz, o);
        ayy += __shfl_xor(ayy, o); ayz += __shfl_xor(ayz, o); azz += __shfl_xor(azz, o);
    }
    if (lane == 0) {
        float2* p = (float2*)(av6 + (size_t)a * 6);
        p[0] = make_float2(axx, axy);
        p[1] = make_float2(axz, ayy);
        p[2] = make_float2(ayz, azz);
    }
    __shared__ float red[4];
    int w = threadIdx.x >> 6;
    if (lane == 0) red[w] = contrib;
    __syncthreads();
    if (threadIdx.x == 0) atomicAdd(&out[OFF_TE], red[0]+red[1]+red[2]+red[3]);
}

__global__ void bwd_send_kernel(const float* __restrict__ vectors,
                                const int* __restrict__ offs_s, const int* __restrict__ eid_s,
                                const float* __restrict__ dr2buf, const float* __restrict__ av6,
                                float* __restrict__ out) {
    int a = (blockIdx.x * blockDim.x + threadIdx.x) >> 6;
    int lane = threadIdx.x & 63;
    int start = offs_s[a], end = offs_s[a + 1];
    float axx=0.f, axy=0.f, axz=0.f, ayy=0.f, ayz=0.f, azz=0.f;
    for (int k = start + lane; k < end; k += 64) {
        int e = eid_s[k];
        float dr2 = dr2buf[e];
        float vx = vectors[3*e], vy = vectors[3*e+1], vz = vectors[3*e+2];
        axx += dr2*vx*vx; axy += dr2*vx*vy; axz += dr2*vx*vz;
        ayy += dr2*vy*vy; ayz += dr2*vy*vz; azz += dr2*vz*vz;
    }
    #pragma unroll
    for (int o = 1; o < 64; o <<= 1) {
        axx += __shfl_xor(axx, o); axy += __shfl_xor(axy, o); axz += __shfl_xor(axz, o);
        ayy += __shfl_xor(ayy, o); ayz += __shfl_xor(ayz, o); azz += __shfl_xor(azz, o);
    }
    if (lane == 0) {
        const float2* p = (const float2*)(av6 + (size_t)a * 6);
        float2 p0 = p[0], p1 = p[1], p2 = p[2];
        axx += p0.x; axy += p0.y; axz += p1.x;
        ayy += p1.y; ayz += p2.x; azz += p2.y;
        float* o9 = out + OFF_AV + (size_t)a * 9;
        o9[0] = axx; o9[1] = axy; o9[2] = axz;
        o9[3] = axy; o9[4] = ayy; o9[5] = ayz;
        o9[6] = axz; o9[7] = ayz; o9[8] = azz;
    }
}

__global__ void virial_reduce(float* __restrict__ out) {
    const float* av = out + OFF_AV;
    float acc[9];
    #pragma unroll
    for (int c = 0; c < 9; ++c) acc[c] = 0.0f;
    for (int n = blockIdx.x * blockDim.x + threadIdx.x; n < N_ATOMS;
         n += gridDim.x * blockDim.x) {
        #pragma unroll
        for (int c = 0; c < 9; ++c) acc[c] += av[n*9 + c];
    }
    __shared__ float red[4];
    int lane = threadIdx.x & 63, wid = threadIdx.x >> 6;
    #pragma unroll
    for (int c = 0; c < 9; ++c) {
        float v = acc[c];
        #pragma unroll
        for (int o = 32; o > 0; o >>= 1) v += __shfl_down(v, o);
        if (lane == 0) red[wid] = v;
        __syncthreads();
        if (threadIdx.x == 0) atomicAdd(&out[OFF_VIR + c], red[0]+red[1]+red[2]+red[3]);
        __syncthreads();
    }
}

// ---------------- launch ----------------

extern "C" void kernel_launch(void* const* d_in, const int* in_sizes, int n_in,
                              void* d_out, int out_size, void* d_ws, size_t ws_size,
                              hipStream_t stream) {
    const float* positions = (const float*)d_in[0];
    const float* vectors   = (const float*)d_in[1];
    const float* lg        = (const float*)d_in[2];
    const float* W1        = (const float*)d_in[3];
    const float* b1        = (const float*)d_in[4];
    const float* W2        = (const float*)d_in[5];
    const float* w3        = (const float*)d_in[6];
    const float* field     = (const float*)d_in[7];
    const float* alphas    = (const float*)d_in[8];
    const int*   edge_index= (const int*)  d_in[9];
    float* out = (float*)d_out;
    int*   wsi = (int*)d_ws;
    float* wsf = (float*)d_ws;

    dim3 blk(256);
    dim3 egrid((N_EDGES + 255) / 256);     // 12500

    if (ws_size >= (size_t)NEND * 4) {
        float*         s_tab  = wsf + NTAB_S;
        float*         g_tab  = wsf + NTAB_G;
        int*           bkc_r8 = wsi + NBKC_R8;
        int*           bkc_s8 = wsi + NBKC_S8;
        int*           bko_r  = wsi + NBKO_R;
        int*           bko_s  = wsi + NBKO_S;
        float*         tepart = wsf + NTEP;
        float*         vpart  = wsf + NVPART;
        float*         av6r   = wsf + NAV6R;
        float4*        stgR   = (float4*)(wsf + NSTGR);
        float4*        stgS   = (float4*)(wsf + NSTGS);
        unsigned char* slS    = (unsigned char*)(wsf + NSLS);

        // bkc_r8 + bkc_s8 contiguous: one memset
        hipMemsetAsync(bkc_r8, 0, (size_t)16 * BPAD * sizeof(int), stream);

        build_tables<<<dim3(NB*HIDDEN/256), blk, 0, stream>>>(W1, b1, alphas, s_tab, g_tab);
        bucket_count<<<egrid, blk, 0, stream>>>(edge_index, bkc_r8, bkc_s8);
        bucket_prefix<<<dim3(2), dim3(1024), 0, stream>>>(bkc_r8, bkc_s8, bko_r, bko_s);
        scatterB<<<egrid, blk, 0, stream>>>(edge_index, bko_r, bkc_r8, vectors, stgR);
        fusedB<<<dim3(NBUCK), dim3(512), 0, stream>>>(stgR, positions, lg, W2, w3, field,
                                                      bko_r, bko_s, bkc_s8, s_tab, g_tab,
                                                      stgS, slS, av6r, tepart, out);
        bwd_sendB<<<dim3(NBUCK), dim3(512), 0, stream>>>(stgS, slS, bko_s, av6r, vpart, out);
        finalize_kernel<<<dim3(1), dim3(1024), 0, stream>>>(tepart, vpart, out);
    } else {
        // fallback: round-3 verified path (67.2 MB ws)
        int*   offs_r = wsi + WOFF_OFFS_R;
        int*   offs_s = wsi + WOFF_OFFS_S;
        int*   rank_r = wsi + WOFF_RANK_R;
        int*   rank_s = wsi + WOFF_RANK_S;
        int*   eid_r  = wsi + WOFF_EID_R;
        int*   eid_s  = wsi + WOFF_EID_S;
        float* dr2buf = wsf + WOFF_DR2;
        float* av6    = wsf + WOFF_AV6;
        dim3 agrid(N_ATOMS / 4);

        hipMemsetAsync(offs_r, 0, (size_t)2 * WPAD * sizeof(int), stream);
        hipMemsetAsync(out + OFF_TE, 0, sizeof(float), stream);
        hipMemsetAsync(out + OFF_VIR, 0, 9 * sizeof(float), stream);

        count_kernel<<<egrid, blk, 0, stream>>>(edge_index, offs_r, offs_s, rank_r, rank_s);
        scan_kernel<<<dim3(2), blk, 0, stream>>>(offs_r, offs_s);
        scatter_kernel<<<egrid, blk, 0, stream>>>(edge_index, offs_r, offs_s,
                                                  rank_r, rank_s, eid_r, eid_s);
        fused_kernel<<<agrid, blk, 0, stream>>>(vectors, positions, lg, W1, b1, W2, w3,
                                                field, alphas, offs_r, eid_r, dr2buf, av6, out);
        bwd_send_kernel<<<agrid, blk, 0, stream>>>(vectors, offs_s, eid_s, dr2buf, av6, out);
        virial_reduce<<<dim3(256), blk, 0, stream>>>(out);
    }
}

// Round 13
// 766.385 us; speedup vs baseline: 1.2193x; 1.2193x over previous
//
#include <hip/hip_runtime.h>

#define N_ATOMS 100000
#define N_EDGES 3200000
#define N_RBF 8
#define HIDDEN 16

#define NB 4096
#define TSCALE 64.0f   // bins per unit r2; table covers r2 in [0, 64)

// d_out layout (floats):
#define OFF_TE   0
#define OFF_NE   1
#define OFF_F    (1 + N_ATOMS)
#define OFF_VIR  (1 + N_ATOMS + 3*N_ATOMS)
#define OFF_AV   (OFF_VIR + 9)

#define WPAD (N_ATOMS + 4)
#define NBLK16 (N_ATOMS / 16)                   // 6250 blocks in fused16/bwd_send16
#define SCAN_B 1024
#define SCAN_NB ((N_ATOMS + SCAN_B) / SCAN_B)   // 98

// two-level recv scatter
#define BSH2   8
#define BATOMS 256
#define NBUCK2 391                              // ceil(100000/256)
#define BPAD2  400

// ---- new-path ws layout (words) ----
#define NTAB_S   0
#define NTAB_G   (NB*HIDDEN)
#define NBKC8    (2*NB*HIDDEN)                  // 131072 ; 8*BPAD2 recv-bucket counters
#define NCNT_S8  (NBKC8 + 8*BPAD2)              // 8 per-XCD send histograms
#define NBKO     (NCNT_S8 + 8*WPAD)             // bucket offsets (NBUCK2+1)
#define NOFF_S   (NBKO + BPAD2)
#define NOFF_R   (NOFF_S + WPAD)
#define NTEP     (NOFF_R + WPAD)
#define NVPART   (NTEP + 6252)
#define NAV6R    (NVPART + 37504)
#define NPAY_R_  (NAV6R + 6*N_ATOMS)
#define NPAY_R   ((NPAY_R_ + 3) & ~3)           // 16B align
#define NSTG1    (NPAY_R + 4*N_EDGES)
#define NDR2V    NSTG1                          // dr2v_s aliases stg1 (dead after part2)
#define NBSUM    NPAY_R                         // scan temp aliases pay_r head
#define NEND     (NSTG1 + 4*N_EDGES)            // ~109.6 MB

// ---- fallback (round-3) ws layout ----
#define WOFF_OFFS_R 0
#define WOFF_OFFS_S WPAD
#define WOFF_RANK_R (2*WPAD)
#define WOFF_RANK_S (WOFF_RANK_R + N_EDGES)
#define WOFF_EID_R  (WOFF_RANK_S + N_EDGES)
#define WOFF_EID_S  (WOFF_EID_R + N_EDGES)
#define WOFF_DR2    (WOFF_EID_S + N_EDGES)
#define WOFF_AV6    (WOFF_DR2 + N_EDGES)
#define WOFF_END    (WOFF_AV6 + 6*N_ATOMS)

typedef float fvec4 __attribute__((ext_vector_type(4)));

__device__ inline void nt_store4(float a, float b, float c, float d, float4* p) {
    fvec4 t;
    t.x = a; t.y = b; t.z = c; t.w = d;
    __builtin_nontemporal_store(t, (fvec4*)p);
}

__device__ inline unsigned int get_xcd() {
    unsigned int xcd;
    asm volatile("s_getreg_b32 %0, hwreg(HW_REG_XCC_ID)" : "=s"(xcd));
    return xcd & 7;
}

// ---------------- table build ----------------
__global__ void build_tables(const float* __restrict__ W1, const float* __restrict__ b1,
                             const float* __restrict__ alphas,
                             float* __restrict__ s_tab, float* __restrict__ g_tab) {
    int idx = blockIdx.x * blockDim.x + threadIdx.x;   // NB*HIDDEN = 65536
    int b = idx >> 4, j = idx & 15;
    float r2 = (float)b / TSCALE;
    float pre = b1[j], pw = 0.f;
    #pragma unroll
    for (int f = 0; f < N_RBF; ++f) {
        float al = alphas[f];
        float ph = __expf(-r2 * al);
        float w  = W1[f*HIDDEN + j];
        pre += ph * w;
        pw  += al * ph * w;
    }
    float sig = 1.f / (1.f + __expf(-pre));
    s_tab[idx] = pre * sig;
    g_tab[idx] = sig * (1.f + pre * (1.f - sig)) * pw;
}

// ---- one pass over ei: recv-bucket histogram + send per-atom histogram ----
// (edge-indexed grid; part1 MUST use the same grid shape so the per-XCD
//  allocator ranges counted here are consumed by the same XCD mapping)

__global__ void count2(const int* __restrict__ ei,
                       int* __restrict__ bkc8, int* __restrict__ cnt_s8) {
    unsigned int xcd = get_xcd();
    int e = blockIdx.x * blockDim.x + threadIdx.x;
    if (e >= N_EDGES) return;
    int send = ei[e], recv = ei[N_EDGES + e];
    __hip_atomic_fetch_add(&bkc8[xcd*BPAD2 + (recv >> BSH2)], 1,
                           __ATOMIC_RELAXED, __HIP_MEMORY_SCOPE_WORKGROUP);
    __hip_atomic_fetch_add(&cnt_s8[xcd*WPAD + send], 1,
                           __ATOMIC_RELAXED, __HIP_MEMORY_SCOPE_WORKGROUP);
}

// bucket prefix: per-XCD exclusive bases in bkc8; bko = exclusive scan of totals
__global__ void bucket_prefix2(int* __restrict__ bkc8, int* __restrict__ bko) {
    int tid = threadIdx.x;
    __shared__ int tot[BPAD2];
    for (int b = tid; b < NBUCK2; b += 1024) {
        int t = 0;
        #pragma unroll
        for (int x = 0; x < 8; ++x) {
            int c = bkc8[x*BPAD2 + b];
            bkc8[x*BPAD2 + b] = t;
            t += c;
        }
        tot[b] = t;
    }
    __syncthreads();
    if (tid == 0) {
        int run = 0;
        for (int b = 0; b < NBUCK2; ++b) { bko[b] = run; run += tot[b]; }
        bko[NBUCK2] = run;
    }
}

__global__ void xcd_prefix_s(int* __restrict__ cnt_s8, int* __restrict__ offs_s) {
    int a = blockIdx.x * blockDim.x + threadIdx.x;
    if (a >= N_ATOMS) return;
    int t = 0;
    #pragma unroll
    for (int x = 0; x < 8; ++x) {
        int c = cnt_s8[x*WPAD + a];
        cnt_s8[x*WPAD + a] = t;
        t += c;
    }
    offs_s[a] = t;
}

// ---- 3-phase exclusive scan over offs_s (N_ATOMS+1) ----

__global__ void scanA1(int* __restrict__ a, int* __restrict__ bsum) {
    const int n = N_ATOMS + 1;
    int i = blockIdx.x * SCAN_B + threadIdx.x;
    int v = (i < n) ? a[i] : 0;
    int lane = threadIdx.x & 63, w = threadIdx.x >> 6;
    int s = v;
    #pragma unroll
    for (int o = 1; o < 64; o <<= 1) {
        int t = __shfl_up(s, o);
        if (lane >= o) s += t;
    }
    __shared__ int wsum[16];
    if (lane == 63) wsum[w] = s;
    __syncthreads();
    if (threadIdx.x < 16) {
        int sc = wsum[threadIdx.x];
        #pragma unroll
        for (int o = 1; o < 16; o <<= 1) {
            int t = __shfl_up(sc, o);
            if ((int)threadIdx.x >= o) sc += t;
        }
        wsum[threadIdx.x] = sc;
    }
    __syncthreads();
    int wpre = (w > 0) ? wsum[w-1] : 0;
    if (i < n) a[i] = s - v + wpre;
    if (threadIdx.x == 0) bsum[blockIdx.x] = wsum[15];
}

__global__ void scanB1(int* __restrict__ bsum) {
    __shared__ int lds[SCAN_NB];
    if (threadIdx.x < SCAN_NB) lds[threadIdx.x] = bsum[threadIdx.x];
    __syncthreads();
    if (threadIdx.x == 0) {
        int run = 0;
        for (int i = 0; i < SCAN_NB; ++i) { int t = lds[i]; lds[i] = run; run += t; }
    }
    __syncthreads();
    if (threadIdx.x < SCAN_NB) bsum[threadIdx.x] = lds[threadIdx.x];
}

__global__ void scanC1(int* __restrict__ a, const int* __restrict__ bsum) {
    int i = blockIdx.x * SCAN_B + threadIdx.x;
    if (i < N_ATOMS + 1) a[i] += bsum[blockIdx.x];
}

// ---- part 1: append to coarse recv buckets; ALSO allocate exact send slot ----
// Same grid shape as count2 => same edge->XCD mapping => allocator ranges match.
// stg1[ps] = (vx,vy,vz, bitcast(ss | recv_lo8<<22)); ss<2^22, recv_lo8<2^8.
__global__ void part1(const int* __restrict__ ei, const int* __restrict__ bko,
                      int* __restrict__ bkc8, int* __restrict__ cnt_s8,
                      const int* __restrict__ offs_s,
                      const float* __restrict__ vectors,
                      float4* __restrict__ stg1) {
    unsigned int xcd = get_xcd();
    int e = blockIdx.x * blockDim.x + threadIdx.x;
    if (e >= N_EDGES) return;
    int send = ei[e], recv = ei[N_EDGES + e];
    int b = recv >> BSH2;
    int p = __hip_atomic_fetch_add(&bkc8[xcd*BPAD2 + b], 1,
                                   __ATOMIC_RELAXED, __HIP_MEMORY_SCOPE_WORKGROUP);
    int ps = bko[b] + p;
    int bs = __hip_atomic_fetch_add(&cnt_s8[xcd*WPAD + send], 1,
                                    __ATOMIC_RELAXED, __HIP_MEMORY_SCOPE_WORKGROUP);
    int ss = offs_s[send] + bs;
    float vx = vectors[3*e], vy = vectors[3*e+1], vz = vectors[3*e+2];
    int packed = ss | ((recv & 255) << 22);
    stg1[ps] = make_float4(vx, vy, vz, __int_as_float(packed));   // plain: L2 tail-merge
}

// ---- part 2: one block per bucket; LDS per-atom CSR; contiguous rewrite ----
// No allocator consumption here (pure block-local placement).

__global__ __launch_bounds__(1024) void part2(const float4* __restrict__ stg1,
                                              const int* __restrict__ bko,
                                              float4* __restrict__ pay_r,
                                              int* __restrict__ offs_r) {
    int b = blockIdx.x;
    int tid = threadIdx.x;
    int base = bko[b], nE = bko[b+1] - base;

    __shared__ int lcnt[BATOMS];
    __shared__ int lincl[BATOMS];
    __shared__ int lalloc[BATOMS];
    __shared__ int wsum4[4];

    if (tid < BATOMS) lcnt[tid] = 0;
    __syncthreads();

    for (int k = tid; k < nE; k += 1024) {
        int pk = __float_as_int(stg1[base + k].w);
        atomicAdd(&lcnt[((unsigned)pk >> 22) & 255], 1);
    }
    __syncthreads();

    if (tid < BATOMS) {
        int v = lcnt[tid];
        int lane = tid & 63, w = tid >> 6;
        int s = v;
        #pragma unroll
        for (int o = 1; o < 64; o <<= 1) {
            int t = __shfl_up(s, o);
            if (lane >= o) s += t;
        }
        lincl[tid] = s;
        if (lane == 63) wsum4[w] = s;
    }
    __syncthreads();
    if (tid < BATOMS) {
        int w = tid >> 6;
        int wpre = 0;
        for (int k = 0; k < w; ++k) wpre += wsum4[k];
        int excl = lincl[tid] - lcnt[tid] + wpre;
        lalloc[tid] = excl;
        int atom = b * BATOMS + tid;
        if (atom <= N_ATOMS) offs_r[atom] = base + excl;
    }
    __syncthreads();

    for (int k = tid; k < nE; k += 1024) {
        float4 p = stg1[base + k];
        int pk = __float_as_int(p.w);
        int rl = ((unsigned)pk >> 22) & 255;
        int ss = pk & 0x3FFFFF;
        int r = atomicAdd(&lalloc[rl], 1);
        pay_r[base + r] = make_float4(p.x, p.y, p.z, __int_as_float(ss));
    }
}

// ---------------- fused: fwd + node MLP + bwd (verbatim round-10) ----------------

__global__ void fused16(const float4* __restrict__ pay_r,
                        const float* __restrict__ positions,
                        const float* __restrict__ lg,
                        const float* __restrict__ W2, const float* __restrict__ w3,
                        const float* __restrict__ field,
                        const int* __restrict__ offs_r,
                        const float* __restrict__ s_tab, const float* __restrict__ g_tab,
                        float4* __restrict__ dr2v_s, float* __restrict__ av6r,
                        float* __restrict__ tepart, float* __restrict__ out) {
    int tid = blockIdx.x * blockDim.x + threadIdx.x;
    int a = tid >> 4;
    int sl = threadIdx.x & 15;
    int lane = threadIdx.x & 63;
    int gb = lane & 48;
    int start = offs_r[a], end = offs_r[a + 1];
    int k0 = start + sl;

    float m[HIDDEN];
    #pragma unroll
    for (int j = 0; j < HIDDEN; ++j) m[j] = 0.f;

    for (int k = k0; k < end; k += 16) {
        float4 p = pay_r[k];
        float r2 = p.x*p.x + p.y*p.y + p.z*p.z;
        float x = fminf(r2 * TSCALE, (float)(NB - 2) + 0.999f);
        int i = (int)x;
        float f = x - (float)i;
        const float4* r0 = (const float4*)(s_tab + i * HIDDEN);
        const float4* r1 = (const float4*)(s_tab + (i + 1) * HIDDEN);
        #pragma unroll
        for (int q = 0; q < 4; ++q) {
            float4 A = r0[q], B = r1[q];
            m[4*q+0] += A.x + f * (B.x - A.x);
            m[4*q+1] += A.y + f * (B.y - A.y);
            m[4*q+2] += A.z + f * (B.z - A.z);
            m[4*q+3] += A.w + f * (B.w - A.w);
        }
    }

    #pragma unroll
    for (int o = 1; o < 16; o <<= 1) {
        #pragma unroll
        for (int j = 0; j < HIDDEN; ++j) m[j] += __shfl_xor(m[j], o);
    }

    float aj = 0.f;
    #pragma unroll
    for (int i = 0; i < HIDDEN; ++i) aj += m[i] * W2[i*HIDDEN + sl];
    float sigj = 1.f / (1.f + __expf(-aj));
    float l = lg[a];
    float w3j = w3[sl];
    float sd = aj * sigj * w3j;
    #pragma unroll
    for (int o = 1; o < 16; o <<= 1) sd += __shfl_xor(sd, o);
    float dAj = l * w3j * sigj * (1.f + aj * (1.f - sigj));
    float gown = 0.f;
    #pragma unroll
    for (int q = 0; q < HIDDEN; ++q) {
        float dq = __shfl(dAj, gb | q);
        gown += dq * W2[sl*HIDDEN + q];
    }
    float g[HIDDEN];
    #pragma unroll
    for (int q = 0; q < HIDDEN; ++q) g[q] = __shfl(gown, gb | q);

    float contrib = 0.f;
    if (sl == 0) {
        float ne = sd + positions[3*a]*field[0] + positions[3*a+1]*field[1]
                      + positions[3*a+2]*field[2];
        out[OFF_NE + a] = ne;
        out[OFF_F + 3*a + 0] = -l * field[0];
        out[OFF_F + 3*a + 1] = -l * field[1];
        out[OFF_F + 3*a + 2] = -l * field[2];
        contrib = ne * l;
    }

    float axx=0.f, axy=0.f, axz=0.f, ayy=0.f, ayz=0.f, azz=0.f;
    for (int k = k0; k < end; k += 16) {
        float4 p = pay_r[k];
        float r2 = p.x*p.x + p.y*p.y + p.z*p.z;
        float x = fminf(r2 * TSCALE, (float)(NB - 2) + 0.999f);
        int i = (int)x;
        float f = x - (float)i;
        const float4* r0 = (const float4*)(g_tab + i * HIDDEN);
        const float4* r1 = (const float4*)(g_tab + (i + 1) * HIDDEN);
        float dr2 = 0.f;
        #pragma unroll
        for (int q = 0; q < 4; ++q) {
            float4 A = r0[q], B = r1[q];
            dr2 -= g[4*q+0] * (A.x + f * (B.x - A.x));
            dr2 -= g[4*q+1] * (A.y + f * (B.y - A.y));
            dr2 -= g[4*q+2] * (A.z + f * (B.z - A.z));
            dr2 -= g[4*q+3] * (A.w + f * (B.w - A.w));
        }
        int ss = __float_as_int(p.w);
        nt_store4(p.x, p.y, p.z, dr2, &dr2v_s[ss]);
        axx += dr2*p.x*p.x; axy += dr2*p.x*p.y; axz += dr2*p.x*p.z;
        ayy += dr2*p.y*p.y; ayz += dr2*p.y*p.z; azz += dr2*p.z*p.z;
    }
    #pragma unroll
    for (int o = 1; o < 16; o <<= 1) {
        axx += __shfl_xor(axx, o); axy += __shfl_xor(axy, o); axz += __shfl_xor(axz, o);
        ayy += __shfl_xor(ayy, o); ayz += __shfl_xor(ayz, o); azz += __shfl_xor(azz, o);
    }
    if (sl == 0) {
        float2* p = (float2*)(av6r + (size_t)a * 6);
        p[0] = make_float2(axx, axy);
        p[1] = make_float2(axz, ayy);
        p[2] = make_float2(ayz, azz);
    }

    __shared__ float red[4];
    if (sl != 0) contrib = 0.f;
    contrib += __shfl_xor(contrib, 16);
    contrib += __shfl_xor(contrib, 32);
    int w = threadIdx.x >> 6;
    if (lane == 0) red[w] = contrib;
    __syncthreads();
    if (threadIdx.x == 0) tepart[blockIdx.x] = red[0]+red[1]+red[2]+red[3];
}

// -------- send-side (verbatim round-10) --------

__global__ void bwd_send16(const float4* __restrict__ dr2v_s,
                           const int* __restrict__ offs_s,
                           const float* __restrict__ av6r,
                           float* __restrict__ vpart, float* __restrict__ out) {
    int tid = blockIdx.x * blockDim.x + threadIdx.x;
    int a = tid >> 4;
    int sl = threadIdx.x & 15;
    int start = offs_s[a], end = offs_s[a + 1];
    float axx=0.f, axy=0.f, axz=0.f, ayy=0.f, ayz=0.f, azz=0.f;
    for (int k = start + sl; k < end; k += 16) {
        float4 q = dr2v_s[k];
        float dr2 = q.w;
        axx += dr2*q.x*q.x; axy += dr2*q.x*q.y; axz += dr2*q.x*q.z;
        ayy += dr2*q.y*q.y; ayz += dr2*q.y*q.z; azz += dr2*q.z*q.z;
    }
    #pragma unroll
    for (int o = 1; o < 16; o <<= 1) {
        axx += __shfl_xor(axx, o); axy += __shfl_xor(axy, o); axz += __shfl_xor(axz, o);
        ayy += __shfl_xor(ayy, o); ayz += __shfl_xor(ayz, o); azz += __shfl_xor(azz, o);
    }
    __shared__ float sh6[16][6];
    int grp = threadIdx.x >> 4;
    if (sl == 0) {
        const float2* p = (const float2*)(av6r + (size_t)a * 6);
        float2 p0 = p[0], p1 = p[1], p2 = p[2];
        axx += p0.x; axy += p0.y; axz += p1.x;
        ayy += p1.y; ayz += p2.x; azz += p2.y;
        float* o9 = out + OFF_AV + (size_t)a * 9;
        o9[0] = axx; o9[1] = axy; o9[2] = axz;
        o9[3] = axy; o9[4] = ayy; o9[5] = ayz;
        o9[6] = axz; o9[7] = ayz; o9[8] = azz;
        sh6[grp][0] = axx; sh6[grp][1] = axy; sh6[grp][2] = axz;
        sh6[grp][3] = ayy; sh6[grp][4] = ayz; sh6[grp][5] = azz;
    }
    __syncthreads();
    if (threadIdx.x < 6) {
        float s = 0.f;
        #pragma unroll
        for (int q = 0; q < 16; ++q) s += sh6[q][threadIdx.x];
        vpart[blockIdx.x * 6 + threadIdx.x] = s;
    }
}

__global__ void finalize_kernel(const float* __restrict__ tepart,
                                const float* __restrict__ vpart,
                                float* __restrict__ out) {
    int t = threadIdx.x;
    float acc[7];
    #pragma unroll
    for (int c = 0; c < 7; ++c) acc[c] = 0.f;
    for (int i = t; i < NBLK16; i += 1024) {
        acc[0] += tepart[i];
        const float* p = vpart + (size_t)i * 6;
        acc[1] += p[0]; acc[2] += p[1]; acc[3] += p[2];
        acc[4] += p[3]; acc[5] += p[4]; acc[6] += p[5];
    }
    #pragma unroll
    for (int c = 0; c < 7; ++c) {
        #pragma unroll
        for (int o = 1; o < 64; o <<= 1) acc[c] += __shfl_xor(acc[c], o);
    }
    __shared__ float sh[16][8];
    int lane = t & 63, w = t >> 6;
    if (lane == 0) {
        #pragma unroll
        for (int c = 0; c < 7; ++c) sh[w][c] = acc[c];
    }
    __syncthreads();
    if (t == 0) {
        float s[7];
        #pragma unroll
        for (int c = 0; c < 7; ++c) {
            float v = 0.f;
            #pragma unroll
            for (int q = 0; q < 16; ++q) v += sh[q][c];
            s[c] = v;
        }
        out[OFF_TE] = s[0];
        out[OFF_VIR + 0] = s[1]; out[OFF_VIR + 1] = s[2]; out[OFF_VIR + 2] = s[3];
        out[OFF_VIR + 3] = s[2]; out[OFF_VIR + 4] = s[4]; out[OFF_VIR + 5] = s[5];
        out[OFF_VIR + 6] = s[3]; out[OFF_VIR + 7] = s[5]; out[OFF_VIR + 8] = s[6];
    }
}

// ================= fallback (round-3 verified path) =================

__global__ void count_kernel(const int* __restrict__ ei,
                             int* __restrict__ cnt_r, int* __restrict__ cnt_s,
                             int* __restrict__ rank_r, int* __restrict__ rank_s) {
    int e = blockIdx.x * blockDim.x + threadIdx.x;
    if (e >= N_EDGES) return;
    int send = ei[e], recv = ei[N_EDGES + e];
    rank_r[e] = atomicAdd(&cnt_r[recv], 1);
    rank_s[e] = atomicAdd(&cnt_s[send], 1);
}

__global__ void scan_kernel(int* __restrict__ offs_r, int* __restrict__ offs_s) {
    int* a = (blockIdx.x == 0) ? offs_r : offs_s;
    const int n = N_ATOMS + 1;
    __shared__ int wsum[4];
    __shared__ int carry_s;
    if (threadIdx.x == 0) carry_s = 0;
    __syncthreads();
    int lane = threadIdx.x & 63, w = threadIdx.x >> 6;
    for (int base = 0; base < n; base += 256) {
        int i = base + threadIdx.x;
        int v = (i < n) ? a[i] : 0;
        int s = v;
        #pragma unroll
        for (int o = 1; o < 64; o <<= 1) {
            int t = __shfl_up(s, o);
            if (lane >= o) s += t;
        }
        if (lane == 63) wsum[w] = s;
        __syncthreads();
        int wpre = 0;
        for (int k = 0; k < w; ++k) wpre += wsum[k];
        int incl = s + wpre;
        int total = wsum[0] + wsum[1] + wsum[2] + wsum[3];
        int excl = incl - v + carry_s;
        if (i < n) a[i] = excl;
        __syncthreads();
        if (threadIdx.x == 0) carry_s += total;
        __syncthreads();
    }
}

__global__ void scatter_kernel(const int* __restrict__ ei,
                               const int* __restrict__ offs_r, const int* __restrict__ offs_s,
                               const int* __restrict__ rank_r, const int* __restrict__ rank_s,
                               int* __restrict__ eid_r, int* __restrict__ eid_s) {
    int e = blockIdx.x * blockDim.x + threadIdx.x;
    if (e >= N_EDGES) return;
    int send = ei[e], recv = ei[N_EDGES + e];
    eid_r[offs_r[recv] + rank_r[e]] = e;
    eid_s[offs_s[send] + rank_s[e]] = e;
}

__global__ void fused_kernel(const float* __restrict__ vectors,
                             const float* __restrict__ positions,
                             const float* __restrict__ lg,
                             const float* __restrict__ W1, const float* __restrict__ b1,
                             const float* __restrict__ W2, const float* __restrict__ w3,
                             const float* __restrict__ field, const float* __restrict__ alphas,
                             const int* __restrict__ offs_r, const int* __restrict__ eid_r,
                             float* __restrict__ dr2buf, float* __restrict__ av6,
                             float* __restrict__ out) {
    int a = (blockIdx.x * blockDim.x + threadIdx.x) >> 6;
    int lane = threadIdx.x & 63;
    int start = offs_r[a], end = offs_r[a + 1];
    float al[N_RBF];
    #pragma unroll
    for (int f = 0; f < N_RBF; ++f) al[f] = alphas[f];
    float m[HIDDEN];
    #pragma unroll
    for (int j = 0; j < HIDDEN; ++j) m[j] = 0.f;
    float t[HIDDEN], paw[HIDDEN];
    float vx0 = 0.f, vy0 = 0.f, vz0 = 0.f;
    int e0 = -1;
    int k0 = start + lane;
    for (int k = k0; k < end; k += 64) {
        int e = eid_r[k];
        float vx = vectors[3*e], vy = vectors[3*e+1], vz = vectors[3*e+2];
        float r2 = vx*vx + vy*vy + vz*vz;
        float phi[N_RBF], apf[N_RBF];
        #pragma unroll
        for (int f = 0; f < N_RBF; ++f) { phi[f] = __expf(-r2 * al[f]); apf[f] = al[f] * phi[f]; }
        bool first = (k == k0);
        if (first) { e0 = e; vx0 = vx; vy0 = vy; vz0 = vz; }
        #pragma unroll
        for (int j = 0; j < HIDDEN; ++j) {
            float pre = b1[j];
            float pw = 0.f;
            #pragma unroll
            for (int f = 0; f < N_RBF; ++f) {
                float w = W1[f*HIDDEN + j];
                pre += phi[f] * w;
                pw  += apf[f] * w;
            }
            float sig = 1.f / (1.f + __expf(-pre));
            m[j] += pre * sig;
            if (first) { t[j] = sig * (1.f + pre * (1.f - sig)); paw[j] = pw; }
        }
    }
    #pragma unroll
    for (int o = 1; o < 64; o <<= 1) {
        #pragma unroll
        for (int j = 0; j < HIDDEN; ++j) m[j] += __shfl_xor(m[j], o);
    }
    int jj = lane & 15;
    int gbase = lane & 48;
    float aj = 0.f;
    #pragma unroll
    for (int i = 0; i < HIDDEN; ++i) aj += m[i] * W2[i*HIDDEN + jj];
    float sigj = 1.f / (1.f + __expf(-aj));
    float l = lg[a];
    float sd = aj * sigj * w3[jj];
    #pragma unroll
    for (int o = 1; o < 16; o <<= 1) sd += __shfl_xor(sd, o);
    float dAj = l * w3[jj] * sigj * (1.f + aj * (1.f - sigj));
    float dAv[HIDDEN];
    #pragma unroll
    for (int q = 0; q < HIDDEN; ++q) dAv[q] = __shfl(dAj, gbase | q);
    float gown = 0.f;
    #pragma unroll
    for (int j2 = 0; j2 < HIDDEN; ++j2) gown += dAv[j2] * W2[jj*HIDDEN + j2];
    float g[HIDDEN];
    #pragma unroll
    for (int q = 0; q < HIDDEN; ++q) g[q] = __shfl(gown, gbase | q);
    float contrib = 0.f;
    if (lane == 0) {
        float ne = sd + positions[3*a]*field[0] + positions[3*a+1]*field[1]
                      + positions[3*a+2]*field[2];
        out[OFF_NE + a] = ne;
        out[OFF_F + 3*a + 0] = -l * field[0];
        out[OFF_F + 3*a + 1] = -l * field[1];
        out[OFF_F + 3*a + 2] = -l * field[2];
        contrib = ne * l;
    }
    float axx=0.f, axy=0.f, axz=0.f, ayy=0.f, ayz=0.f, azz=0.f;
    if (k0 < end) {
        float dr2 = 0.f;
        #pragma unroll
        for (int j = 0; j < HIDDEN; ++j) dr2 -= (g[j] * t[j]) * paw[j];
        dr2buf[e0] = dr2;
        axx = dr2*vx0*vx0; axy = dr2*vx0*vy0; axz = dr2*vx0*vz0;
        ayy = dr2*vy0*vy0; ayz = dr2*vy0*vz0; azz = dr2*vz0*vz0;
    }
    for (int k = k0 + 64; k < end; k += 64) {
        int e = eid_r[k];
        float vx = vectors[3*e], vy = vectors[3*e+1], vz = vectors[3*e+2];
        float r2 = vx*vx + vy*vy + vz*vz;
        float phi[N_RBF], apf[N_RBF];
        #pragma unroll
        for (int f = 0; f < N_RBF; ++f) { phi[f] = __expf(-r2 * al[f]); apf[f] = al[f] * phi[f]; }
        float dr2 = 0.f;
        #pragma unroll
        for (int j = 0; j < HIDDEN; ++j) {
            float pre = b1[j];
            float pw = 0.f;
            #pragma unroll
            for (int f = 0; f < N_RBF; ++f) {
                float w = W1[f*HIDDEN + j];
                pre += phi[f] * w;
                pw  += apf[f] * w;
            }
            float sig = 1.f / (1.f + __expf(-pre));
            float tt = sig * (1.f + pre * (1.f - sig));
            dr2 -= (g[j] * tt) * pw;
        }
        dr2buf[e] = dr2;
        axx += dr2*vx*vx; axy += dr2*vx*vy; axz += dr2*vx*vz;
        ayy += dr2*vy*vy; ayz += dr2*vy*vz; azz += dr2*vz*vz;
    }
    #pragma unroll
    for (int o = 1; o < 64; o <<= 1) {
        axx += __shfl_xor(axx, o); axy += __shfl_xor(axy, o); axz += __shfl_xor(axz, o);
        ayy += __shfl_xor(ayy, o); ayz += __shfl_xor(ayz, o); azz += __shfl_xor(azz, o);
    }
    if (lane == 0) {
        float2* p = (float2*)(av6 + (size_t)a * 6);
        p[0] = make_float2(axx, axy);
        p[1] = make_float2(axz, ayy);
        p[2] = make_float2(ayz, azz);
    }
    __shared__ float red[4];
    int w = threadIdx.x >> 6;
    if (lane == 0) red[w] = contrib;
    __syncthreads();
    if (threadIdx.x == 0) atomicAdd(&out[OFF_TE], red[0]+red[1]+red[2]+red[3]);
}

__global__ void bwd_send_kernel(const float* __restrict__ vectors,
                                const int* __restrict__ offs_s, const int* __restrict__ eid_s,
                                const float* __restrict__ dr2buf, const float* __restrict__ av6,
                                float* __restrict__ out) {
    int a = (blockIdx.x * blockDim.x + threadIdx.x) >> 6;
    int lane = threadIdx.x & 63;
    int start = offs_s[a], end = offs_s[a + 1];
    float axx=0.f, axy=0.f, axz=0.f, ayy=0.f, ayz=0.f, azz=0.f;
    for (int k = start + lane; k < end; k += 64) {
        int e = eid_s[k];
        float dr2 = dr2buf[e];
        float vx = vectors[3*e], vy = vectors[3*e+1], vz = vectors[3*e+2];
        axx += dr2*vx*vx; axy += dr2*vx*vy; axz += dr2*vx*vz;
        ayy += dr2*vy*vy; ayz += dr2*vy*vz; azz += dr2*vz*vz;
    }
    #pragma unroll
    for (int o = 1; o < 64; o <<= 1) {
        axx += __shfl_xor(axx, o); axy += __shfl_xor(axy, o); axz += __shfl_xor(axz, o);
        ayy += __shfl_xor(ayy, o); ayz += __shfl_xor(ayz, o); azz += __shfl_xor(azz, o);
    }
    if (lane == 0) {
        const float2* p = (const float2*)(av6 + (size_t)a * 6);
        float2 p0 = p[0], p1 = p[1], p2 = p[2];
        axx += p0.x; axy += p0.y; axz += p1.x;
        ayy += p1.y; ayz += p2.x; azz += p2.y;
        float* o9 = out + OFF_AV + (size_t)a * 9;
        o9[0] = axx; o9[1] = axy; o9[2] = axz;
        o9[3] = axy; o9[4] = ayy; o9[5] = ayz;
        o9[6] = axz; o9[7] = ayz; o9[8] = azz;
    }
}

__global__ void virial_reduce(float* __restrict__ out) {
    const float* av = out + OFF_AV;
    float acc[9];
    #pragma unroll
    for (int c = 0; c < 9; ++c) acc[c] = 0.0f;
    for (int n = blockIdx.x * blockDim.x + threadIdx.x; n < N_ATOMS;
         n += gridDim.x * blockDim.x) {
        #pragma unroll
        for (int c = 0; c < 9; ++c) acc[c] += av[n*9 + c];
    }
    __shared__ float red[4];
    int lane = threadIdx.x & 63, wid = threadIdx.x >> 6;
    #pragma unroll
    for (int c = 0; c < 9; ++c) {
        float v = acc[c];
        #pragma unroll
        for (int o = 32; o > 0; o >>= 1) v += __shfl_down(v, o);
        if (lane == 0) red[wid] = v;
        __syncthreads();
        if (threadIdx.x == 0) atomicAdd(&out[OFF_VIR + c], red[0]+red[1]+red[2]+red[3]);
        __syncthreads();
    }
}

// ---------------- launch ----------------

extern "C" void kernel_launch(void* const* d_in, const int* in_sizes, int n_in,
                              void* d_out, int out_size, void* d_ws, size_t ws_size,
                              hipStream_t stream) {
    const float* positions = (const float*)d_in[0];
    const float* vectors   = (const float*)d_in[1];
    const float* lg        = (const float*)d_in[2];
    const float* W1        = (const float*)d_in[3];
    const float* b1        = (const float*)d_in[4];
    const float* W2        = (const float*)d_in[5];
    const float* w3        = (const float*)d_in[6];
    const float* field     = (const float*)d_in[7];
    const float* alphas    = (const float*)d_in[8];
    const int*   edge_index= (const int*)  d_in[9];
    float* out = (float*)d_out;
    int*   wsi = (int*)d_ws;
    float* wsf = (float*)d_ws;

    dim3 blk(256);
    dim3 egrid((N_EDGES + 255) / 256);     // 12500
    dim3 g16(NBLK16);                      // 6250

    if (ws_size >= (size_t)NEND * 4) {
        float*  s_tab  = wsf + NTAB_S;
        float*  g_tab  = wsf + NTAB_G;
        int*    bkc8   = wsi + NBKC8;
        int*    cnt_s8 = wsi + NCNT_S8;
        int*    bko    = wsi + NBKO;
        int*    offs_s = wsi + NOFF_S;
        int*    offs_r = wsi + NOFF_R;
        float*  tepart = wsf + NTEP;
        float*  vpart  = wsf + NVPART;
        float*  av6r   = wsf + NAV6R;
        float4* pay_r  = (float4*)(wsf + NPAY_R);
        float4* stg1   = (float4*)(wsf + NSTG1);
        float4* dr2v_s = (float4*)(wsf + NDR2V);   // aliases stg1 (dead after part2)
        int*    bsum   = wsi + NBSUM;              // aliases pay_r head

        // zero: bkc8, cnt_s8, bko, offs_s (contiguous region)
        hipMemsetAsync(bkc8, 0,
                       (size_t)(8*BPAD2 + 8*WPAD + BPAD2 + WPAD) * sizeof(int), stream);

        build_tables<<<dim3(NB*HIDDEN/256), blk, 0, stream>>>(W1, b1, alphas, s_tab, g_tab);
        count2<<<egrid, blk, 0, stream>>>(edge_index, bkc8, cnt_s8);
        bucket_prefix2<<<dim3(1), dim3(1024), 0, stream>>>(bkc8, bko);
        xcd_prefix_s<<<dim3((N_ATOMS+255)/256), blk, 0, stream>>>(cnt_s8, offs_s);
        scanA1<<<dim3(SCAN_NB), dim3(SCAN_B), 0, stream>>>(offs_s, bsum);
        scanB1<<<dim3(1), dim3(128), 0, stream>>>(bsum);
        scanC1<<<dim3(SCAN_NB), dim3(SCAN_B), 0, stream>>>(offs_s, bsum);
        part1<<<egrid, blk, 0, stream>>>(edge_index, bko, bkc8, cnt_s8, offs_s,
                                         vectors, stg1);
        part2<<<dim3(NBUCK2), dim3(1024), 0, stream>>>(stg1, bko, pay_r, offs_r);
        fused16<<<g16, blk, 0, stream>>>(pay_r, positions, lg, W2, w3, field,
                                         offs_r, s_tab, g_tab, dr2v_s, av6r, tepart, out);
        bwd_send16<<<g16, blk, 0, stream>>>(dr2v_s, offs_s, av6r, vpart, out);
        finalize_kernel<<<dim3(1), dim3(1024), 0, stream>>>(tepart, vpart, out);
    } else {
        // fallback: round-3 verified path (67.2 MB ws)
        int*   offs_r = wsi + WOFF_OFFS_R;
        int*   offs_s = wsi + WOFF_OFFS_S;
        int*   rank_r = wsi + WOFF_RANK_R;
        int*   rank_s = wsi + WOFF_RANK_S;
        int*   eid_r  = wsi + WOFF_EID_R;
        int*   eid_s  = wsi + WOFF_EID_S;
        float* dr2buf = wsf + WOFF_DR2;
        float* av6    = wsf + WOFF_AV6;
        dim3 agrid(N_ATOMS / 4);

        hipMemsetAsync(offs_r, 0, (size_t)2 * WPAD * sizeof(int), stream);
        hipMemsetAsync(out + OFF_TE, 0, sizeof(float), stream);
        hipMemsetAsync(out + OFF_VIR, 0, 9 * sizeof(float), stream);

        count_kernel<<<egrid, blk, 0, stream>>>(edge_index, offs_r, offs_s, rank_r, rank_s);
        scan_kernel<<<dim3(2), blk, 0, stream>>>(offs_r, offs_s);
        scatter_kernel<<<egrid, blk, 0, stream>>>(edge_index, offs_r, offs_s,
                                                  rank_r, rank_s, eid_r, eid_s);
        fused_kernel<<<agrid, blk, 0, stream>>>(vectors, positions, lg, W1, b1, W2, w3,
                                                field, alphas, offs_r, eid_r, dr2buf, av6, out);
        bwd_send_kernel<<<agrid, blk, 0, stream>>>(vectors, offs_s, eid_s, dr2buf, av6, out);
        virial_reduce<<<dim3(256), blk, 0, stream>>>(out);
    }
}

// Round 14
// 689.464 us; speedup vs baseline: 1.3553x; 1.1116x over previous
//
#include <hip/hip_runtime.h>

#define N_ATOMS 100000
#define N_EDGES 3200000
#define N_RBF 8
#define HIDDEN 16

#define NB 4096
#define TSCALE 64.0f   // bins per unit r2; table covers r2 in [0, 64)

// d_out layout (floats):
#define OFF_TE   0
#define OFF_NE   1
#define OFF_F    (1 + N_ATOMS)
#define OFF_VIR  (1 + N_ATOMS + 3*N_ATOMS)
#define OFF_AV   (OFF_VIR + 9)

#define WPAD (N_ATOMS + 4)
#define NBLK16 (N_ATOMS / 16)                   // 6250 blocks in fused16/bwd_send16
#define SCAN_B 1024
#define SCAN_NB ((N_ATOMS + SCAN_B) / SCAN_B)   // 98 blocks cover N_ATOMS+1

// ---- new-path ws layout (words) ----
#define NTAB_S   0
#define NTAB_G   (NB*HIDDEN)
#define NOFF_R   (2*NB*HIDDEN)                 // 131072
#define NOFF_S   (NOFF_R + WPAD)
#define NCNT_R8  (NOFF_S + WPAD)               // 8 per-XCD histograms (recv)
#define NCNT_S8  (NCNT_R8 + 8*WPAD)            // 8 per-XCD histograms (send)
#define NTEP     (NCNT_S8 + 8*WPAD)            // 1,931,144
#define NVPART   (NTEP + 8192)
#define NAV6R    (NVPART + 40960)              // recv-side float partials, 6*N
#define NPAY_R   (NAV6R + 6*N_ATOMS)           // 2,580,296 (16B aligned)
#define NDR2V    (NPAY_R + 4*N_EDGES)          // 15,380,296 (16B aligned)
#define NBSUM    NPAY_R                        // scan temp aliases pay_r head
#define NEND     (NDR2V + 4*N_EDGES)           // 28,180,296 words = 112.7 MB

// ---- fallback (round-3) ws layout ----
#define WOFF_OFFS_R 0
#define WOFF_OFFS_S WPAD
#define WOFF_RANK_R (2*WPAD)
#define WOFF_RANK_S (WOFF_RANK_R + N_EDGES)
#define WOFF_EID_R  (WOFF_RANK_S + N_EDGES)
#define WOFF_EID_S  (WOFF_EID_R + N_EDGES)
#define WOFF_DR2    (WOFF_EID_S + N_EDGES)
#define WOFF_AV6    (WOFF_DR2 + N_EDGES)
#define WOFF_END    (WOFF_AV6 + 6*N_ATOMS)

__device__ inline unsigned int get_xcd() {
    unsigned int xcd;
    asm volatile("s_getreg_b32 %0, hwreg(HW_REG_XCC_ID)" : "=s"(xcd));
    return xcd & 7;
}

// ---------------- table build ----------------
__global__ void build_tables(const float* __restrict__ W1, const float* __restrict__ b1,
                             const float* __restrict__ alphas,
                             float* __restrict__ s_tab, float* __restrict__ g_tab) {
    int idx = blockIdx.x * blockDim.x + threadIdx.x;   // NB*HIDDEN = 65536
    int b = idx >> 4, j = idx & 15;
    float r2 = (float)b / TSCALE;
    float pre = b1[j], pw = 0.f;
    #pragma unroll
    for (int f = 0; f < N_RBF; ++f) {
        float al = alphas[f];
        float ph = __expf(-r2 * al);
        float w  = W1[f*HIDDEN + j];
        pre += ph * w;
        pw  += al * ph * w;
    }
    float sig = 1.f / (1.f + __expf(-pre));
    s_tab[idx] = pre * sig;
    g_tab[idx] = sig * (1.f + pre * (1.f - sig)) * pw;
}

// ---------------- CSR build: per-XCD histograms, L2-local int atomics ----------------

__global__ void count8_kernel(const int* __restrict__ ei,
                              int* __restrict__ cnt_r8, int* __restrict__ cnt_s8) {
    unsigned int xcd = get_xcd();
    int e = blockIdx.x * blockDim.x + threadIdx.x;
    if (e >= N_EDGES) return;
    int send = ei[e], recv = ei[N_EDGES + e];
    __hip_atomic_fetch_add(&cnt_r8[xcd * WPAD + recv], 1,
                           __ATOMIC_RELAXED, __HIP_MEMORY_SCOPE_WORKGROUP);
    __hip_atomic_fetch_add(&cnt_s8[xcd * WPAD + send], 1,
                           __ATOMIC_RELAXED, __HIP_MEMORY_SCOPE_WORKGROUP);
}

__global__ void xcd_prefix_kernel(int* __restrict__ cnt_r8, int* __restrict__ cnt_s8,
                                  int* __restrict__ offs_r, int* __restrict__ offs_s) {
    int a = blockIdx.x * blockDim.x + threadIdx.x;
    if (a >= N_ATOMS) return;
    int t = 0;
    #pragma unroll
    for (int x = 0; x < 8; ++x) {
        int c = cnt_r8[x*WPAD + a];
        cnt_r8[x*WPAD + a] = t;
        t += c;
    }
    offs_r[a] = t;
    t = 0;
    #pragma unroll
    for (int x = 0; x < 8; ++x) {
        int c = cnt_s8[x*WPAD + a];
        cnt_s8[x*WPAD + a] = t;
        t += c;
    }
    offs_s[a] = t;
}

// ---------------- parallel 3-phase exclusive scan over N_ATOMS+1 (both arrays) ----

__global__ void scanA(int* __restrict__ offs_r, int* __restrict__ offs_s,
                      int* __restrict__ bsum) {
    int y = blockIdx.y;
    int* a = y ? offs_s : offs_r;
    const int n = N_ATOMS + 1;
    int i = blockIdx.x * SCAN_B + threadIdx.x;
    int v = (i < n) ? a[i] : 0;
    int lane = threadIdx.x & 63, w = threadIdx.x >> 6;
    int s = v;
    #pragma unroll
    for (int o = 1; o < 64; o <<= 1) {
        int t = __shfl_up(s, o);
        if (lane >= o) s += t;
    }
    __shared__ int wsum[16];
    if (lane == 63) wsum[w] = s;
    __syncthreads();
    if (threadIdx.x < 16) {
        int sc = wsum[threadIdx.x];
        #pragma unroll
        for (int o = 1; o < 16; o <<= 1) {
            int t = __shfl_up(sc, o);
            if ((int)threadIdx.x >= o) sc += t;
        }
        wsum[threadIdx.x] = sc;
    }
    __syncthreads();
    int wpre = (w > 0) ? wsum[w-1] : 0;
    if (i < n) a[i] = s - v + wpre;
    if (threadIdx.x == 0) bsum[y * SCAN_NB + blockIdx.x] = wsum[15];
}

__global__ void scanB(int* __restrict__ bsum) {
    __shared__ int lds[SCAN_NB];
    for (int y = 0; y < 2; ++y) {
        if (threadIdx.x < SCAN_NB) lds[threadIdx.x] = bsum[y*SCAN_NB + threadIdx.x];
        __syncthreads();
        if (threadIdx.x == 0) {
            int run = 0;
            for (int i = 0; i < SCAN_NB; ++i) { int t = lds[i]; lds[i] = run; run += t; }
        }
        __syncthreads();
        if (threadIdx.x < SCAN_NB) bsum[y*SCAN_NB + threadIdx.x] = lds[threadIdx.x];
        __syncthreads();
    }
}

__global__ void scanC(int* __restrict__ offs_r, int* __restrict__ offs_s,
                      const int* __restrict__ bsum) {
    int y = blockIdx.y;
    int* a = y ? offs_s : offs_r;
    int i = blockIdx.x * SCAN_B + threadIdx.x;
    if (i < N_ATOMS + 1) a[i] += bsum[y*SCAN_NB + blockIdx.x];
}

// ---------------- scatter: allocator-style, SINGLE payload, PLAIN stores ----------------
// pay_r[rs] = (vx,vy,vz, bitcast(send_slot ss)). Plain (write-back) stores let
// same-line touches from the same XCD merge in its L2 (round-13 part1 evidence:
// plain cut WRITE_SIZE 302->216 MB with no RFO fetch increase).
__global__ void scatter1(const int* __restrict__ ei,
                         const int* __restrict__ offs_r, const int* __restrict__ offs_s,
                         int* __restrict__ cnt_r8, int* __restrict__ cnt_s8,
                         const float* __restrict__ vectors,
                         float4* __restrict__ pay_r) {
    unsigned int xcd = get_xcd();
    int e = blockIdx.x * blockDim.x + threadIdx.x;
    if (e >= N_EDGES) return;
    int send = ei[e], recv = ei[N_EDGES + e];
    int br = __hip_atomic_fetch_add(&cnt_r8[xcd*WPAD + recv], 1,
                                    __ATOMIC_RELAXED, __HIP_MEMORY_SCOPE_WORKGROUP);
    int rs = offs_r[recv] + br;
    int bs = __hip_atomic_fetch_add(&cnt_s8[xcd*WPAD + send], 1,
                                    __ATOMIC_RELAXED, __HIP_MEMORY_SCOPE_WORKGROUP);
    int ss = offs_s[send] + bs;
    float vx = vectors[3*e], vy = vectors[3*e+1], vz = vectors[3*e+2];
    pay_r[rs] = make_float4(vx, vy, vz, __int_as_float(ss));
}

// ---------------- fused: fwd + node MLP + bwd; dr2v scattered to send slots ----

__global__ void fused16(const float4* __restrict__ pay_r,
                        const float* __restrict__ positions,
                        const float* __restrict__ lg,
                        const float* __restrict__ W2, const float* __restrict__ w3,
                        const float* __restrict__ field,
                        const int* __restrict__ offs_r,
                        const float* __restrict__ s_tab, const float* __restrict__ g_tab,
                        float4* __restrict__ dr2v_s, float* __restrict__ av6r,
                        float* __restrict__ tepart, float* __restrict__ out) {
    int tid = blockIdx.x * blockDim.x + threadIdx.x;
    int a = tid >> 4;
    int sl = threadIdx.x & 15;
    int lane = threadIdx.x & 63;
    int gb = lane & 48;
    int start = offs_r[a], end = offs_r[a + 1];
    int k0 = start + sl;

    float m[HIDDEN];
    #pragma unroll
    for (int j = 0; j < HIDDEN; ++j) m[j] = 0.f;

    // ---- pass 1: forward via S-table ----
    for (int k = k0; k < end; k += 16) {
        float4 p = pay_r[k];
        float r2 = p.x*p.x + p.y*p.y + p.z*p.z;
        float x = fminf(r2 * TSCALE, (float)(NB - 2) + 0.999f);
        int i = (int)x;
        float f = x - (float)i;
        const float4* r0 = (const float4*)(s_tab + i * HIDDEN);
        const float4* r1 = (const float4*)(s_tab + (i + 1) * HIDDEN);
        #pragma unroll
        for (int q = 0; q < 4; ++q) {
            float4 A = r0[q], B = r1[q];
            m[4*q+0] += A.x + f * (B.x - A.x);
            m[4*q+1] += A.y + f * (B.y - A.y);
            m[4*q+2] += A.z + f * (B.z - A.z);
            m[4*q+3] += A.w + f * (B.w - A.w);
        }
    }

    #pragma unroll
    for (int o = 1; o < 16; o <<= 1) {
        #pragma unroll
        for (int j = 0; j < HIDDEN; ++j) m[j] += __shfl_xor(m[j], o);
    }

    // ---- node MLP, channel j = sl per lane ----
    float aj = 0.f;
    #pragma unroll
    for (int i = 0; i < HIDDEN; ++i) aj += m[i] * W2[i*HIDDEN + sl];
    float sigj = 1.f / (1.f + __expf(-aj));
    float l = lg[a];
    float w3j = w3[sl];
    float sd = aj * sigj * w3j;
    #pragma unroll
    for (int o = 1; o < 16; o <<= 1) sd += __shfl_xor(sd, o);
    float dAj = l * w3j * sigj * (1.f + aj * (1.f - sigj));
    float gown = 0.f;
    #pragma unroll
    for (int q = 0; q < HIDDEN; ++q) {
        float dq = __shfl(dAj, gb | q);
        gown += dq * W2[sl*HIDDEN + q];
    }
    float g[HIDDEN];
    #pragma unroll
    for (int q = 0; q < HIDDEN; ++q) g[q] = __shfl(gown, gb | q);

    float contrib = 0.f;
    if (sl == 0) {
        float ne = sd + positions[3*a]*field[0] + positions[3*a+1]*field[1]
                      + positions[3*a+2]*field[2];
        out[OFF_NE + a] = ne;
        out[OFF_F + 3*a + 0] = -l * field[0];
        out[OFF_F + 3*a + 1] = -l * field[1];
        out[OFF_F + 3*a + 2] = -l * field[2];
        contrib = ne * l;
    }

    // ---- pass 2: backward via G-table; (v,dr2) scattered to send slot (plain store) ----
    float axx=0.f, axy=0.f, axz=0.f, ayy=0.f, ayz=0.f, azz=0.f;
    for (int k = k0; k < end; k += 16) {
        float4 p = pay_r[k];
        float r2 = p.x*p.x + p.y*p.y + p.z*p.z;
        float x = fminf(r2 * TSCALE, (float)(NB - 2) + 0.999f);
        int i = (int)x;
        float f = x - (float)i;
        const float4* r0 = (const float4*)(g_tab + i * HIDDEN);
        const float4* r1 = (const float4*)(g_tab + (i + 1) * HIDDEN);
        float dr2 = 0.f;
        #pragma unroll
        for (int q = 0; q < 4; ++q) {
            float4 A = r0[q], B = r1[q];
            dr2 -= g[4*q+0] * (A.x + f * (B.x - A.x));
            dr2 -= g[4*q+1] * (A.y + f * (B.y - A.y));
            dr2 -= g[4*q+2] * (A.z + f * (B.z - A.z));
            dr2 -= g[4*q+3] * (A.w + f * (B.w - A.w));
        }
        int ss = __float_as_int(p.w);
        dr2v_s[ss] = make_float4(p.x, p.y, p.z, dr2);   // plain: L2 write-merge
        axx += dr2*p.x*p.x; axy += dr2*p.x*p.y; axz += dr2*p.x*p.z;
        ayy += dr2*p.y*p.y; ayz += dr2*p.y*p.z; azz += dr2*p.z*p.z;
    }
    #pragma unroll
    for (int o = 1; o < 16; o <<= 1) {
        axx += __shfl_xor(axx, o); axy += __shfl_xor(axy, o); axz += __shfl_xor(axz, o);
        ayy += __shfl_xor(ayy, o); ayz += __shfl_xor(ayz, o); azz += __shfl_xor(azz, o);
    }
    if (sl == 0) {
        float2* p = (float2*)(av6r + (size_t)a * 6);
        p[0] = make_float2(axx, axy);
        p[1] = make_float2(axz, ayy);
        p[2] = make_float2(ayz, azz);
    }

    // total-energy block partial (no global atomic)
    __shared__ float red[4];
    if (sl != 0) contrib = 0.f;
    contrib += __shfl_xor(contrib, 16);
    contrib += __shfl_xor(contrib, 32);
    int w = threadIdx.x >> 6;
    if (lane == 0) red[w] = contrib;
    __syncthreads();
    if (threadIdx.x == 0) tepart[blockIdx.x] = red[0]+red[1]+red[2]+red[3];
}

// -------- send-side: fully coalesced single-stream; block virial partials --------

__global__ void bwd_send16(const float4* __restrict__ dr2v_s,
                           const int* __restrict__ offs_s,
                           const float* __restrict__ av6r,
                           float* __restrict__ vpart, float* __restrict__ out) {
    int tid = blockIdx.x * blockDim.x + threadIdx.x;
    int a = tid >> 4;
    int sl = threadIdx.x & 15;
    int start = offs_s[a], end = offs_s[a + 1];
    float axx=0.f, axy=0.f, axz=0.f, ayy=0.f, ayz=0.f, azz=0.f;
    for (int k = start + sl; k < end; k += 16) {
        float4 q = dr2v_s[k];
        float dr2 = q.w;
        axx += dr2*q.x*q.x; axy += dr2*q.x*q.y; axz += dr2*q.x*q.z;
        ayy += dr2*q.y*q.y; ayz += dr2*q.y*q.z; azz += dr2*q.z*q.z;
    }
    #pragma unroll
    for (int o = 1; o < 16; o <<= 1) {
        axx += __shfl_xor(axx, o); axy += __shfl_xor(axy, o); axz += __shfl_xor(axz, o);
        ayy += __shfl_xor(ayy, o); ayz += __shfl_xor(ayz, o); azz += __shfl_xor(azz, o);
    }
    __shared__ float sh6[16][6];
    int grp = threadIdx.x >> 4;
    if (sl == 0) {
        const float2* p = (const float2*)(av6r + (size_t)a * 6);
        float2 p0 = p[0], p1 = p[1], p2 = p[2];
        axx += p0.x; axy += p0.y; axz += p1.x;
        ayy += p1.y; ayz += p2.x; azz += p2.y;
        float* o9 = out + OFF_AV + (size_t)a * 9;
        o9[0] = axx; o9[1] = axy; o9[2] = axz;
        o9[3] = axy; o9[4] = ayy; o9[5] = ayz;
        o9[6] = axz; o9[7] = ayz; o9[8] = azz;
        sh6[grp][0] = axx; sh6[grp][1] = axy; sh6[grp][2] = axz;
        sh6[grp][3] = ayy; sh6[grp][4] = ayz; sh6[grp][5] = azz;
    }
    __syncthreads();
    if (threadIdx.x < 6) {
        float s = 0.f;
        #pragma unroll
        for (int q = 0; q < 16; ++q) s += sh6[q][threadIdx.x];
        vpart[blockIdx.x * 6 + threadIdx.x] = s;
    }
}

// -------- final reduce of TE + virial partials: one block, plain stores --------

__global__ void finalize_kernel(const float* __restrict__ tepart,
                                const float* __restrict__ vpart,
                                float* __restrict__ out) {
    int t = threadIdx.x;
    float acc[7];
    #pragma unroll
    for (int c = 0; c < 7; ++c) acc[c] = 0.f;
    for (int i = t; i < NBLK16; i += 1024) {
        acc[0] += tepart[i];
        const float* p = vpart + (size_t)i * 6;
        acc[1] += p[0]; acc[2] += p[1]; acc[3] += p[2];
        acc[4] += p[3]; acc[5] += p[4]; acc[6] += p[5];
    }
    #pragma unroll
    for (int c = 0; c < 7; ++c) {
        #pragma unroll
        for (int o = 1; o < 64; o <<= 1) acc[c] += __shfl_xor(acc[c], o);
    }
    __shared__ float sh[16][8];
    int lane = t & 63, w = t >> 6;
    if (lane == 0) {
        #pragma unroll
        for (int c = 0; c < 7; ++c) sh[w][c] = acc[c];
    }
    __syncthreads();
    if (t == 0) {
        float s[7];
        #pragma unroll
        for (int c = 0; c < 7; ++c) {
            float v = 0.f;
            #pragma unroll
            for (int q = 0; q < 16; ++q) v += sh[q][c];
            s[c] = v;
        }
        out[OFF_TE] = s[0];
        out[OFF_VIR + 0] = s[1]; out[OFF_VIR + 1] = s[2]; out[OFF_VIR + 2] = s[3];
        out[OFF_VIR + 3] = s[2]; out[OFF_VIR + 4] = s[4]; out[OFF_VIR + 5] = s[5];
        out[OFF_VIR + 6] = s[3]; out[OFF_VIR + 7] = s[5]; out[OFF_VIR + 8] = s[6];
    }
}

// ================= fallback (round-3 verified path) =================

__global__ void count_kernel(const int* __restrict__ ei,
                             int* __restrict__ cnt_r, int* __restrict__ cnt_s,
                             int* __restrict__ rank_r, int* __restrict__ rank_s) {
    int e = blockIdx.x * blockDim.x + threadIdx.x;
    if (e >= N_EDGES) return;
    int send = ei[e], recv = ei[N_EDGES + e];
    rank_r[e] = atomicAdd(&cnt_r[recv], 1);
    rank_s[e] = atomicAdd(&cnt_s[send], 1);
}

__global__ void scan_kernel(int* __restrict__ offs_r, int* __restrict__ offs_s) {
    int* a = (blockIdx.x == 0) ? offs_r : offs_s;
    const int n = N_ATOMS + 1;
    __shared__ int wsum[4];
    __shared__ int carry_s;
    if (threadIdx.x == 0) carry_s = 0;
    __syncthreads();
    int lane = threadIdx.x & 63, w = threadIdx.x >> 6;
    for (int base = 0; base < n; base += 256) {
        int i = base + threadIdx.x;
        int v = (i < n) ? a[i] : 0;
        int s = v;
        #pragma unroll
        for (int o = 1; o < 64; o <<= 1) {
            int t = __shfl_up(s, o);
            if (lane >= o) s += t;
        }
        if (lane == 63) wsum[w] = s;
        __syncthreads();
        int wpre = 0;
        for (int k = 0; k < w; ++k) wpre += wsum[k];
        int incl = s + wpre;
        int total = wsum[0] + wsum[1] + wsum[2] + wsum[3];
        int excl = incl - v + carry_s;
        if (i < n) a[i] = excl;
        __syncthreads();
        if (threadIdx.x == 0) carry_s += total;
        __syncthreads();
    }
}

__global__ void scatter_kernel(const int* __restrict__ ei,
                               const int* __restrict__ offs_r, const int* __restrict__ offs_s,
                               const int* __restrict__ rank_r, const int* __restrict__ rank_s,
                               int* __restrict__ eid_r, int* __restrict__ eid_s) {
    int e = blockIdx.x * blockDim.x + threadIdx.x;
    if (e >= N_EDGES) return;
    int send = ei[e], recv = ei[N_EDGES + e];
    eid_r[offs_r[recv] + rank_r[e]] = e;
    eid_s[offs_s[send] + rank_s[e]] = e;
}

__global__ void fused_kernel(const float* __restrict__ vectors,
                             const float* __restrict__ positions,
                             const float* __restrict__ lg,
                             const float* __restrict__ W1, const float* __restrict__ b1,
                             const float* __restrict__ W2, const float* __restrict__ w3,
                             const float* __restrict__ field, const float* __restrict__ alphas,
                             const int* __restrict__ offs_r, const int* __restrict__ eid_r,
                             float* __restrict__ dr2buf, float* __restrict__ av6,
                             float* __restrict__ out) {
    int a = (blockIdx.x * blockDim.x + threadIdx.x) >> 6;
    int lane = threadIdx.x & 63;
    int start = offs_r[a], end = offs_r[a + 1];
    float al[N_RBF];
    #pragma unroll
    for (int f = 0; f < N_RBF; ++f) al[f] = alphas[f];
    float m[HIDDEN];
    #pragma unroll
    for (int j = 0; j < HIDDEN; ++j) m[j] = 0.f;
    float t[HIDDEN], paw[HIDDEN];
    float vx0 = 0.f, vy0 = 0.f, vz0 = 0.f;
    int e0 = -1;
    int k0 = start + lane;
    for (int k = k0; k < end; k += 64) {
        int e = eid_r[k];
        float vx = vectors[3*e], vy = vectors[3*e+1], vz = vectors[3*e+2];
        float r2 = vx*vx + vy*vy + vz*vz;
        float phi[N_RBF], apf[N_RBF];
        #pragma unroll
        for (int f = 0; f < N_RBF; ++f) { phi[f] = __expf(-r2 * al[f]); apf[f] = al[f] * phi[f]; }
        bool first = (k == k0);
        if (first) { e0 = e; vx0 = vx; vy0 = vy; vz0 = vz; }
        #pragma unroll
        for (int j = 0; j < HIDDEN; ++j) {
            float pre = b1[j];
            float pw = 0.f;
            #pragma unroll
            for (int f = 0; f < N_RBF; ++f) {
                float w = W1[f*HIDDEN + j];
                pre += phi[f] * w;
                pw  += apf[f] * w;
            }
            float sig = 1.f / (1.f + __expf(-pre));
            m[j] += pre * sig;
            if (first) { t[j] = sig * (1.f + pre * (1.f - sig)); paw[j] = pw; }
        }
    }
    #pragma unroll
    for (int o = 1; o < 64; o <<= 1) {
        #pragma unroll
        for (int j = 0; j < HIDDEN; ++j) m[j] += __shfl_xor(m[j], o);
    }
    int jj = lane & 15;
    int gbase = lane & 48;
    float aj = 0.f;
    #pragma unroll
    for (int i = 0; i < HIDDEN; ++i) aj += m[i] * W2[i*HIDDEN + jj];
    float sigj = 1.f / (1.f + __expf(-aj));
    float l = lg[a];
    float sd = aj * sigj * w3[jj];
    #pragma unroll
    for (int o = 1; o < 16; o <<= 1) sd += __shfl_xor(sd, o);
    float dAj = l * w3[jj] * sigj * (1.f + aj * (1.f - sigj));
    float dAv[HIDDEN];
    #pragma unroll
    for (int q = 0; q < HIDDEN; ++q) dAv[q] = __shfl(dAj, gbase | q);
    float gown = 0.f;
    #pragma unroll
    for (int j2 = 0; j2 < HIDDEN; ++j2) gown += dAv[j2] * W2[jj*HIDDEN + j2];
    float g[HIDDEN];
    #pragma unroll
    for (int q = 0; q < HIDDEN; ++q) g[q] = __shfl(gown, gbase | q);
    float contrib = 0.f;
    if (lane == 0) {
        float ne = sd + positions[3*a]*field[0] + positions[3*a+1]*field[1]
                      + positions[3*a+2]*field[2];
        out[OFF_NE + a] = ne;
        out[OFF_F + 3*a + 0] = -l * field[0];
        out[OFF_F + 3*a + 1] = -l * field[1];
        out[OFF_F + 3*a + 2] = -l * field[2];
        contrib = ne * l;
    }
    float axx=0.f, axy=0.f, axz=0.f, ayy=0.f, ayz=0.f, azz=0.f;
    if (k0 < end) {
        float dr2 = 0.f;
        #pragma unroll
        for (int j = 0; j < HIDDEN; ++j) dr2 -= (g[j] * t[j]) * paw[j];
        dr2buf[e0] = dr2;
        axx = dr2*vx0*vx0; axy = dr2*vx0*vy0; axz = dr2*vx0*vz0;
        ayy = dr2*vy0*vy0; ayz = dr2*vy0*vz0; azz = dr2*vz0*vz0;
    }
    for (int k = k0 + 64; k < end; k += 64) {
        int e = eid_r[k];
        float vx = vectors[3*e], vy = vectors[3*e+1], vz = vectors[3*e+2];
        float r2 = vx*vx + vy*vy + vz*vz;
        float phi[N_RBF], apf[N_RBF];
        #pragma unroll
        for (int f = 0; f < N_RBF; ++f) { phi[f] = __expf(-r2 * al[f]); apf[f] = al[f] * phi[f]; }
        float dr2 = 0.f;
        #pragma unroll
        for (int j = 0; j < HIDDEN; ++j) {
            float pre = b1[j];
            float pw = 0.f;
            #pragma unroll
            for (int f = 0; f < N_RBF; ++f) {
                float w = W1[f*HIDDEN + j];
                pre += phi[f] * w;
                pw  += apf[f] * w;
            }
            float sig = 1.f / (1.f + __expf(-pre));
            float tt = sig * (1.f + pre * (1.f - sig));
            dr2 -= (g[j] * tt) * pw;
        }
        dr2buf[e] = dr2;
        axx += dr2*vx*vx; axy += dr2*vx*vy; axz += dr2*vx*vz;
        ayy += dr2*vy*vy; ayz += dr2*vy*vz; azz += dr2*vz*vz;
    }
    #pragma unroll
    for (int o = 1; o < 64; o <<= 1) {
        axx += __shfl_xor(axx, o); axy += __shfl_xor(axy, o); axz += __shfl_xor(axz, o);
        ayy += __shfl_xor(ayy, o); ayz += __shfl_xor(ayz, o); azz += __shfl_xor(azz, o);
    }
    if (lane == 0) {
        float2* p = (float2*)(av6 + (size_t)a * 6);
        p[0] = make_float2(axx, axy);
        p[1] = make_float2(axz, ayy);
        p[2] = make_float2(ayz, azz);
    }
    __shared__ float red[4];
    int w = threadIdx.x >> 6;
    if (lane == 0) red[w] = contrib;
    __syncthreads();
    if (threadIdx.x == 0) atomicAdd(&out[OFF_TE], red[0]+red[1]+red[2]+red[3]);
}

__global__ void bwd_send_kernel(const float* __restrict__ vectors,
                                const int* __restrict__ offs_s, const int* __restrict__ eid_s,
                                const float* __restrict__ dr2buf, const float* __restrict__ av6,
                                float* __restrict__ out) {
    int a = (blockIdx.x * blockDim.x + threadIdx.x) >> 6;
    int lane = threadIdx.x & 63;
    int start = offs_s[a], end = offs_s[a + 1];
    float axx=0.f, axy=0.f, axz=0.f, ayy=0.f, ayz=0.f, azz=0.f;
    for (int k = start + lane; k < end; k += 64) {
        int e = eid_s[k];
        float dr2 = dr2buf[e];
        float vx = vectors[3*e], vy = vectors[3*e+1], vz = vectors[3*e+2];
        axx += dr2*vx*vx; axy += dr2*vx*vy; axz += dr2*vx*vz;
        ayy += dr2*vy*vy; ayz += dr2*vy*vz; azz += dr2*vz*vz;
    }
    #pragma unroll
    for (int o = 1; o < 64; o <<= 1) {
        axx += __shfl_xor(axx, o); axy += __shfl_xor(axy, o); axz += __shfl_xor(axz, o);
        ayy += __shfl_xor(ayy, o); ayz += __shfl_xor(ayz, o); azz += __shfl_xor(azz, o);
    }
    if (lane == 0) {
        const float2* p = (const float2*)(av6 + (size_t)a * 6);
        float2 p0 = p[0], p1 = p[1], p2 = p[2];
        axx += p0.x; axy += p0.y; axz += p1.x;
        ayy += p1.y; ayz += p2.x; azz += p2.y;
        float* o9 = out + OFF_AV + (size_t)a * 9;
        o9[0] = axx; o9[1] = axy; o9[2] = axz;
        o9[3] = axy; o9[4] = ayy; o9[5] = ayz;
        o9[6] = axz; o9[7] = ayz; o9[8] = azz;
    }
}

__global__ void virial_reduce(float* __restrict__ out) {
    const float* av = out + OFF_AV;
    float acc[9];
    #pragma unroll
    for (int c = 0; c < 9; ++c) acc[c] = 0.0f;
    for (int n = blockIdx.x * blockDim.x + threadIdx.x; n < N_ATOMS;
         n += gridDim.x * blockDim.x) {
        #pragma unroll
        for (int c = 0; c < 9; ++c) acc[c] += av[n*9 + c];
    }
    __shared__ float red[4];
    int lane = threadIdx.x & 63, wid = threadIdx.x >> 6;
    #pragma unroll
    for (int c = 0; c < 9; ++c) {
        float v = acc[c];
        #pragma unroll
        for (int o = 32; o > 0; o >>= 1) v += __shfl_down(v, o);
        if (lane == 0) red[wid] = v;
        __syncthreads();
        if (threadIdx.x == 0) atomicAdd(&out[OFF_VIR + c], red[0]+red[1]+red[2]+red[3]);
        __syncthreads();
    }
}

// ---------------- launch ----------------

extern "C" void kernel_launch(void* const* d_in, const int* in_sizes, int n_in,
                              void* d_out, int out_size, void* d_ws, size_t ws_size,
                              hipStream_t stream) {
    const float* positions = (const float*)d_in[0];
    const float* vectors   = (const float*)d_in[1];
    const float* lg        = (const float*)d_in[2];
    const float* W1        = (const float*)d_in[3];
    const float* b1        = (const float*)d_in[4];
    const float* W2        = (const float*)d_in[5];
    const float* w3        = (const float*)d_in[6];
    const float* field     = (const float*)d_in[7];
    const float* alphas    = (const float*)d_in[8];
    const int*   edge_index= (const int*)  d_in[9];
    float* out = (float*)d_out;
    int*   wsi = (int*)d_ws;
    float* wsf = (float*)d_ws;

    dim3 blk(256);
    dim3 egrid((N_EDGES + 255) / 256);     // 12500
    dim3 g16(NBLK16);                      // 6250 blocks, 16 lanes/atom

    if (ws_size >= (size_t)NEND * 4) {
        float*  s_tab  = wsf + NTAB_S;
        float*  g_tab  = wsf + NTAB_G;
        int*    offs_r = wsi + NOFF_R;
        int*    offs_s = wsi + NOFF_S;
        int*    cnt_r8 = wsi + NCNT_R8;
        int*    cnt_s8 = wsi + NCNT_S8;
        float*  tepart = wsf + NTEP;
        float*  vpart  = wsf + NVPART;
        float*  av6r   = wsf + NAV6R;
        float4* pay_r  = (float4*)(wsf + NPAY_R);
        float4* dr2v_s = (float4*)(wsf + NDR2V);
        int*    bsum   = wsi + NBSUM;      // aliases pay_r head (dead before scatter)

        // offs_r, offs_s, cnt_r8, cnt_s8 contiguous: one memset
        hipMemsetAsync(offs_r, 0, (size_t)18 * WPAD * sizeof(int), stream);

        build_tables<<<dim3(NB*HIDDEN/256), blk, 0, stream>>>(W1, b1, alphas, s_tab, g_tab);
        count8_kernel<<<egrid, blk, 0, stream>>>(edge_index, cnt_r8, cnt_s8);
        xcd_prefix_kernel<<<dim3((N_ATOMS+255)/256), blk, 0, stream>>>(cnt_r8, cnt_s8,
                                                                       offs_r, offs_s);
        scanA<<<dim3(SCAN_NB, 2), dim3(SCAN_B), 0, stream>>>(offs_r, offs_s, bsum);
        scanB<<<dim3(1), dim3(256), 0, stream>>>(bsum);
        scanC<<<dim3(SCAN_NB, 2), dim3(SCAN_B), 0, stream>>>(offs_r, offs_s, bsum);
        scatter1<<<egrid, blk, 0, stream>>>(edge_index, offs_r, offs_s,
                                            cnt_r8, cnt_s8, vectors, pay_r);
        fused16<<<g16, blk, 0, stream>>>(pay_r, positions, lg, W2, w3, field,
                                         offs_r, s_tab, g_tab, dr2v_s, av6r, tepart, out);
        bwd_send16<<<g16, blk, 0, stream>>>(dr2v_s, offs_s, av6r, vpart, out);
        finalize_kernel<<<dim3(1), dim3(1024), 0, stream>>>(tepart, vpart, out);
    } else {
        // fallback: round-3 verified path (67.2 MB ws)
        int*   offs_r = wsi + WOFF_OFFS_R;
        int*   offs_s = wsi + WOFF_OFFS_S;
        int*   rank_r = wsi + WOFF_RANK_R;
        int*   rank_s = wsi + WOFF_RANK_S;
        int*   eid_r  = wsi + WOFF_EID_R;
        int*   eid_s  = wsi + WOFF_EID_S;
        float* dr2buf = wsf + WOFF_DR2;
        float* av6    = wsf + WOFF_AV6;
        dim3 agrid(N_ATOMS / 4);

        hipMemsetAsync(offs_r, 0, (size_t)2 * WPAD * sizeof(int), stream);
        hipMemsetAsync(out + OFF_TE, 0, sizeof(float), stream);
        hipMemsetAsync(out + OFF_VIR, 0, 9 * sizeof(float), stream);

        count_kernel<<<egrid, blk, 0, stream>>>(edge_index, offs_r, offs_s, rank_r, rank_s);
        scan_kernel<<<dim3(2), blk, 0, stream>>>(offs_r, offs_s);
        scatter_kernel<<<egrid, blk, 0, stream>>>(edge_index, offs_r, offs_s,
                                                  rank_r, rank_s, eid_r, eid_s);
        fused_kernel<<<agrid, blk, 0, stream>>>(vectors, positions, lg, W1, b1, W2, w3,
                                                field, alphas, offs_r, eid_r, dr2buf, av6, out);
        bwd_send_kernel<<<agrid, blk, 0, stream>>>(vectors, offs_s, eid_s, dr2buf, av6, out);
        virial_reduce<<<dim3(256), blk, 0, stream>>>(out);
    }
}